// Round 1
// baseline (862.267 us; speedup 1.0000x reference)
//
#include <hip/hip_runtime.h>
#include <math.h>

#define N_NODES 50176
#define N_EDGES 802816
#define HIDDEN  128
#define NGRAPH  64
#define BN_EPS  1e-5f
#define ATT_SCALE 0.08838834764831845f  // 1/sqrt(128)

// ---------------- CSR build ----------------
__global__ void hist_kernel(const int* __restrict__ dst, int* __restrict__ cnt) {
    int e = blockIdx.x * 256 + threadIdx.x;
    if (e < N_EDGES) atomicAdd(&cnt[dst[e]], 1);
}

// 49 blocks x 256 threads, 4 elems/thread = 1024/block; 49*1024 == 50176 exactly.
__global__ void scan1_kernel(const int* __restrict__ cnt, int* __restrict__ row_ptr,
                             int* __restrict__ bsum) {
    __shared__ int sh[256];
    int t = threadIdx.x, b = blockIdx.x;
    int base = b * 1024 + t * 4;
    int v0 = cnt[base], v1 = cnt[base + 1], v2 = cnt[base + 2], v3 = cnt[base + 3];
    int tot = v0 + v1 + v2 + v3;
    sh[t] = tot; __syncthreads();
    for (int off = 1; off < 256; off <<= 1) {
        int x = (t >= off) ? sh[t - off] : 0;
        __syncthreads();
        sh[t] += x;
        __syncthreads();
    }
    int excl = sh[t] - tot;
    row_ptr[base]     = excl;
    row_ptr[base + 1] = excl + v0;
    row_ptr[base + 2] = excl + v0 + v1;
    row_ptr[base + 3] = excl + v0 + v1 + v2;
    if (t == 255) bsum[b] = sh[255];
}

__global__ void scan2_kernel(const int* __restrict__ bsum, int* __restrict__ boff,
                             int* __restrict__ row_ptr) {
    int acc = 0;
    for (int i = 0; i < 49; i++) { boff[i] = acc; acc += bsum[i]; }
    row_ptr[N_NODES] = acc;  // == N_EDGES
}

__global__ void scan3_kernel(int* __restrict__ row_ptr, int* __restrict__ cur,
                             const int* __restrict__ boff) {
    int t = threadIdx.x, b = blockIdx.x;
    int base = b * 1024 + t * 4;
    int off = boff[b];
    #pragma unroll
    for (int j = 0; j < 4; j++) {
        int v = row_ptr[base + j] + off;
        row_ptr[base + j] = v;
        cur[base + j] = v;
    }
}

__global__ void scatter_kernel(const int* __restrict__ src, const int* __restrict__ dst,
                               int* __restrict__ cur, int* __restrict__ edge_src) {
    int e = blockIdx.x * 256 + threadIdx.x;
    if (e < N_EDGES) {
        int d = dst[e];
        int slot = atomicAdd(&cur[d], 1);
        edge_src[slot] = src[e];
    }
}

// ---------------- Fused projection GEMM: [N,128] x [128,512] (Q|K|V|S) ----------------
// 64x64 output tile, 256 threads, 4x4 micro-tile. Optional fused BN+ReLU on input load.
__global__ __launch_bounds__(256) void gemm_qkvs(
    const float* __restrict__ in,
    const float* __restrict__ Wq, const float* __restrict__ Wk,
    const float* __restrict__ Wv, const float* __restrict__ Ws,
    const float* __restrict__ bq, const float* __restrict__ bk,
    const float* __restrict__ bv, const float* __restrict__ bs,
    float* __restrict__ qb, float* __restrict__ kb,
    float* __restrict__ vb, float* __restrict__ hb,
    const float* __restrict__ bnA, const float* __restrict__ bnB)
{
    __shared__ float As[64][128];
    __shared__ float Bs[128][64];
    int t = threadIdx.x;
    int n0 = blockIdx.x * 64;
    int c0 = blockIdx.y * 64;          // 0,64,...,448
    int m  = c0 >> 7;                  // which matrix
    int cbase = c0 & 127;              // 0 or 64
    const float* W    = (m == 0) ? Wq : (m == 1) ? Wk : (m == 2) ? Wv : Ws;
    const float* bias = (m == 0) ? bq : (m == 1) ? bk : (m == 2) ? bv : bs;
    float* outb       = (m == 0) ? qb : (m == 1) ? kb : (m == 2) ? vb : hb;

    // stage A (with optional bn+relu)
    {
        int r  = t >> 5;          // 0..7
        int kq = (t & 31) * 4;    // 0..124
        float4 ba = make_float4(1.f, 1.f, 1.f, 1.f);
        float4 bb = make_float4(0.f, 0.f, 0.f, 0.f);
        if (bnA) {
            ba = *reinterpret_cast<const float4*>(&bnA[kq]);
            bb = *reinterpret_cast<const float4*>(&bnB[kq]);
        }
        #pragma unroll
        for (int p = 0; p < 8; p++) {
            int row = n0 + r + p * 8;
            float4 v = *reinterpret_cast<const float4*>(&in[row * 128 + kq]);
            if (bnA) {
                v.x = fmaxf(v.x * ba.x + bb.x, 0.f);
                v.y = fmaxf(v.y * ba.y + bb.y, 0.f);
                v.z = fmaxf(v.z * ba.z + bb.z, 0.f);
                v.w = fmaxf(v.w * ba.w + bb.w, 0.f);
            }
            *reinterpret_cast<float4*>(&As[r + p * 8][kq]) = v;
        }
    }
    // stage B
    {
        int kk = t >> 4;          // 0..15
        int cc = (t & 15) * 4;    // 0..60
        #pragma unroll
        for (int p = 0; p < 8; p++) {
            int k = kk + p * 16;
            float4 v = *reinterpret_cast<const float4*>(&W[k * 128 + cbase + cc]);
            *reinterpret_cast<float4*>(&Bs[k][cc]) = v;
        }
    }
    __syncthreads();

    int ty = t >> 4, tx = t & 15;
    float acc[4][4] = {};
    #pragma unroll 4
    for (int k4 = 0; k4 < 32; k4++) {
        float a[4][4], bvv[4][4];
        #pragma unroll
        for (int i = 0; i < 4; i++) {
            float4 av = *reinterpret_cast<const float4*>(&As[ty * 4 + i][k4 * 4]);
            a[i][0] = av.x; a[i][1] = av.y; a[i][2] = av.z; a[i][3] = av.w;
        }
        #pragma unroll
        for (int kk = 0; kk < 4; kk++) {
            float4 bv4 = *reinterpret_cast<const float4*>(&Bs[k4 * 4 + kk][tx * 4]);
            bvv[kk][0] = bv4.x; bvv[kk][1] = bv4.y; bvv[kk][2] = bv4.z; bvv[kk][3] = bv4.w;
        }
        #pragma unroll
        for (int kk = 0; kk < 4; kk++)
            #pragma unroll
            for (int i = 0; i < 4; i++)
                #pragma unroll
                for (int j = 0; j < 4; j++)
                    acc[i][j] += a[i][kk] * bvv[kk][j];
    }

    float4 bi = *reinterpret_cast<const float4*>(&bias[cbase + tx * 4]);
    #pragma unroll
    for (int i = 0; i < 4; i++) {
        int row = n0 + ty * 4 + i;
        float4 o;
        o.x = acc[i][0] + bi.x;
        o.y = acc[i][1] + bi.y;
        o.z = acc[i][2] + bi.z;
        o.w = acc[i][3] + bi.w;
        *reinterpret_cast<float4*>(&outb[row * 128 + cbase + tx * 4]) = o;
    }
}

// ---------------- Per-node attention aggregation (wave per node) ----------------
__global__ __launch_bounds__(256) void agg_kernel(
    const float* __restrict__ qb, const float* __restrict__ kb, const float* __restrict__ vb,
    const int* __restrict__ row_ptr, const int* __restrict__ edge_src,
    float* __restrict__ hb)
{
    int wave = threadIdx.x >> 6, lane = threadIdx.x & 63;
    int n = blockIdx.x * 4 + wave;
    float2 q2 = *reinterpret_cast<const float2*>(&qb[n * 128 + lane * 2]);
    int s0 = row_ptr[n], s1 = row_ptr[n + 1];
    float acc0 = 0.f, acc1 = 0.f, ssum = 0.f;
    for (int j = s0; j < s1; j++) {
        int s = edge_src[j];
        float2 k2 = *reinterpret_cast<const float2*>(&kb[s * 128 + lane * 2]);
        float part = q2.x * k2.x + q2.y * k2.y;
        #pragma unroll
        for (int o = 1; o < 64; o <<= 1) part += __shfl_xor(part, o, 64);
        float w = __expf(part * ATT_SCALE);
        float2 v2 = *reinterpret_cast<const float2*>(&vb[s * 128 + lane * 2]);
        ssum += w;
        acc0 += w * v2.x;
        acc1 += w * v2.y;
    }
    float inv = 1.0f / (ssum + 1e-16f);
    float2 h = *reinterpret_cast<float2*>(&hb[n * 128 + lane * 2]);
    h.x += acc0 * inv;
    h.y += acc1 * inv;
    *reinterpret_cast<float2*>(&hb[n * 128 + lane * 2]) = h;
}

// ---------------- BatchNorm statistics ----------------
__global__ __launch_bounds__(256) void bn_stats(const float* __restrict__ h,
                                                float* __restrict__ sums,
                                                float* __restrict__ sqs) {
    int t = threadIdx.x;
    int c = t & 127;
    float s = 0.f, q = 0.f;
    int stride = gridDim.x * 256;
    for (int i = blockIdx.x * 256 + t; i < N_NODES * 128; i += stride) {
        float v = h[i];
        s += v; q += v * v;
    }
    __shared__ float sh[256], shq[256];
    sh[t] = s; shq[t] = q;
    __syncthreads();
    if (t < 128) {
        atomicAdd(&sums[c], sh[t] + sh[t + 128]);
        atomicAdd(&sqs[c],  shq[t] + shq[t + 128]);
    }
}

__global__ void bn_final(const float* __restrict__ sums, const float* __restrict__ sqs,
                         const float* __restrict__ g, const float* __restrict__ be,
                         float* __restrict__ a, float* __restrict__ b) {
    int c = threadIdx.x;
    float mean = sums[c] / (float)N_NODES;
    float var  = sqs[c] / (float)N_NODES - mean * mean;
    float inv  = rsqrtf(var + BN_EPS);
    float av   = g[c] * inv;
    a[c] = av;
    b[c] = be[c] - mean * av;
}

// ---------------- Final FC head (2 nodes per 256-thread block) ----------------
__global__ __launch_bounds__(256) void fc_kernel(
    const float* __restrict__ h2, const float* __restrict__ a1, const float* __restrict__ b1,
    const int* __restrict__ ptr, const float* __restrict__ gf,
    const float* __restrict__ fcW, const float* __restrict__ fcb,
    const float* __restrict__ fc2W, const float* __restrict__ fc2b,
    float* __restrict__ out)
{
    __shared__ float hc[2][144];
    __shared__ float red[2][128];
    int t = threadIdx.x;
    int local = t >> 7;       // 0..1
    int o = t & 127;
    int n = blockIdx.x * 2 + local;

    float v = h2[n * 128 + o];
    hc[local][o] = fmaxf(a1[o] * v + b1[o], 0.f);
    if (o < 16) {
        // graph_id = searchsorted(ptr, n, 'right') - 1
        int lo = 0, hi = NGRAPH;
        while (lo < hi) {
            int mid = (lo + hi + 1) >> 1;
            if (ptr[mid] <= n) lo = mid; else hi = mid - 1;
        }
        hc[local][128 + o] = gf[lo * 16 + o];
    }
    __syncthreads();

    float acc = fcb[o];
    #pragma unroll 16
    for (int i = 0; i < 144; i++) acc += hc[local][i] * fcW[i * 128 + o];
    acc = fmaxf(acc, 0.f);
    red[local][o] = acc * fc2W[o];
    __syncthreads();
    for (int off = 64; off > 0; off >>= 1) {
        if (o < off) red[local][o] += red[local][o + off];
        __syncthreads();
    }
    if (o == 0) out[n] = red[local][0] + fc2b[0];
}

// ---------------- launch ----------------
extern "C" void kernel_launch(void* const* d_in, const int* in_sizes, int n_in,
                              void* d_out, int out_size, void* d_ws, size_t ws_size,
                              hipStream_t stream)
{
    const float* x   = (const float*)d_in[0];
    const int*   ei  = (const int*)d_in[1];
    const int*   ptr = (const int*)d_in[2];
    const float* gf  = (const float*)d_in[3];
    const float* Wq0 = (const float*)d_in[4];
    const float* Wk0 = (const float*)d_in[5];
    const float* Wv0 = (const float*)d_in[6];
    const float* Ws0 = (const float*)d_in[7];
    const float* bq0 = (const float*)d_in[8];
    const float* bk0 = (const float*)d_in[9];
    const float* bv0 = (const float*)d_in[10];
    const float* bs0 = (const float*)d_in[11];
    const float* g0  = (const float*)d_in[12];
    const float* be0 = (const float*)d_in[13];
    const float* Wq1 = (const float*)d_in[14];
    const float* Wk1 = (const float*)d_in[15];
    const float* Wv1 = (const float*)d_in[16];
    const float* Ws1 = (const float*)d_in[17];
    const float* bq1 = (const float*)d_in[18];
    const float* bk1 = (const float*)d_in[19];
    const float* bv1 = (const float*)d_in[20];
    const float* bs1 = (const float*)d_in[21];
    const float* g1  = (const float*)d_in[22];
    const float* be1 = (const float*)d_in[23];
    const float* fcW = (const float*)d_in[24];
    const float* fcb = (const float*)d_in[25];
    const float* fc2W= (const float*)d_in[26];
    const float* fc2b= (const float*)d_in[27];
    float* out = (float*)d_out;

    const int* src_p = ei;            // edge_index[0]
    const int* dst_p = ei + N_EDGES;  // edge_index[1]

    char* w = (char*)d_ws;
    const size_t NM = (size_t)N_NODES * 128 * sizeof(float);
    float* qb = (float*)w;            w += NM;
    float* kb = (float*)w;            w += NM;
    float* vb = (float*)w;            w += NM;
    float* h1 = (float*)w;            w += NM;
    float* h2 = (float*)w;            w += NM;
    float* stats = (float*)w;         w += 1024 * sizeof(float);
    float* sums0 = stats;             // 128
    float* sqs0  = stats + 128;
    float* sums1 = stats + 256;
    float* sqs1  = stats + 384;
    float* a0    = stats + 512;
    float* b0    = stats + 640;
    float* a1    = stats + 768;
    float* b1    = stats + 896;
    int* cnt     = (int*)w;           w += (size_t)N_NODES * sizeof(int);
    int* row_ptr = (int*)w;           w += (size_t)(N_NODES + 1) * sizeof(int);
    int* cur     = (int*)w;           w += (size_t)N_NODES * sizeof(int);
    int* edge_src= (int*)w;           w += (size_t)N_EDGES * sizeof(int);
    int* bsum    = (int*)w;           w += 64 * sizeof(int);
    int* boff    = (int*)w;           w += 64 * sizeof(int);

    hipMemsetAsync(cnt, 0, (size_t)N_NODES * sizeof(int), stream);
    hipMemsetAsync(stats, 0, 512 * sizeof(float), stream);

    // CSR build (reused by both layers)
    hist_kernel<<<3136, 256, 0, stream>>>(dst_p, cnt);
    scan1_kernel<<<49, 256, 0, stream>>>(cnt, row_ptr, bsum);
    scan2_kernel<<<1, 1, 0, stream>>>(bsum, boff, row_ptr);
    scan3_kernel<<<49, 256, 0, stream>>>(row_ptr, cur, boff);
    scatter_kernel<<<3136, 256, 0, stream>>>(src_p, dst_p, cur, edge_src);

    // Layer 0
    gemm_qkvs<<<dim3(784, 8), 256, 0, stream>>>(x, Wq0, Wk0, Wv0, Ws0,
        bq0, bk0, bv0, bs0, qb, kb, vb, h1, nullptr, nullptr);
    agg_kernel<<<12544, 256, 0, stream>>>(qb, kb, vb, row_ptr, edge_src, h1);
    bn_stats<<<784, 256, 0, stream>>>(h1, sums0, sqs0);
    bn_final<<<1, 128, 0, stream>>>(sums0, sqs0, g0, be0, a0, b0);

    // Layer 1 (BN+ReLU fused into GEMM input load)
    gemm_qkvs<<<dim3(784, 8), 256, 0, stream>>>(h1, Wq1, Wk1, Wv1, Ws1,
        bq1, bk1, bv1, bs1, qb, kb, vb, h2, a0, b0);
    agg_kernel<<<12544, 256, 0, stream>>>(qb, kb, vb, row_ptr, edge_src, h2);
    bn_stats<<<784, 256, 0, stream>>>(h2, sums1, sqs1);
    bn_final<<<1, 128, 0, stream>>>(sums1, sqs1, g1, be1, a1, b1);

    // Head: BN+ReLU + concat(global) + FC + ReLU + FC2
    fc_kernel<<<25088, 256, 0, stream>>>(h2, a1, b1, ptr, gf,
        fcW, fcb, fc2W, fc2b, out);
}

// Round 2
// 646.551 us; speedup vs baseline: 1.3336x; 1.3336x over previous
//
#include <hip/hip_runtime.h>
#include <math.h>

#define N_NODES 50176
#define N_EDGES 802816
#define HIDDEN  128
#define NGRAPH  64
#define BN_EPS  1e-5f
#define ATT_SCALE 0.08838834764831845f  // 1/sqrt(128)

__device__ __forceinline__ float bflo(unsigned u) { return __uint_as_float(u << 16); }
__device__ __forceinline__ float bfhi(unsigned u) { return __uint_as_float(u & 0xffff0000u); }
__device__ __forceinline__ unsigned short f2bf(float f) {
    unsigned u = __float_as_uint(f);
    unsigned r = (u + 0x7fffu + ((u >> 16) & 1u)) >> 16;
    return (unsigned short)r;
}

// ---------------- CSR build ----------------
__global__ void hist_kernel(const int* __restrict__ dst, int* __restrict__ cnt) {
    int e = blockIdx.x * 256 + threadIdx.x;
    if (e < N_EDGES) atomicAdd(&cnt[dst[e]], 1);
}

__global__ void scan1_kernel(const int* __restrict__ cnt, int* __restrict__ row_ptr,
                             int* __restrict__ bsum) {
    __shared__ int sh[256];
    int t = threadIdx.x, b = blockIdx.x;
    int base = b * 1024 + t * 4;
    int v0 = cnt[base], v1 = cnt[base + 1], v2 = cnt[base + 2], v3 = cnt[base + 3];
    int tot = v0 + v1 + v2 + v3;
    sh[t] = tot; __syncthreads();
    for (int off = 1; off < 256; off <<= 1) {
        int x = (t >= off) ? sh[t - off] : 0;
        __syncthreads();
        sh[t] += x;
        __syncthreads();
    }
    int excl = sh[t] - tot;
    row_ptr[base]     = excl;
    row_ptr[base + 1] = excl + v0;
    row_ptr[base + 2] = excl + v0 + v1;
    row_ptr[base + 3] = excl + v0 + v1 + v2;
    if (t == 255) bsum[b] = sh[255];
}

__global__ void scan2_kernel(const int* __restrict__ bsum, int* __restrict__ boff,
                             int* __restrict__ row_ptr) {
    int acc = 0;
    for (int i = 0; i < 49; i++) { boff[i] = acc; acc += bsum[i]; }
    row_ptr[N_NODES] = acc;
}

__global__ void scan3_kernel(int* __restrict__ row_ptr, int* __restrict__ cur,
                             const int* __restrict__ boff) {
    int t = threadIdx.x, b = blockIdx.x;
    int base = b * 1024 + t * 4;
    int off = boff[b];
    #pragma unroll
    for (int j = 0; j < 4; j++) {
        int v = row_ptr[base + j] + off;
        row_ptr[base + j] = v;
        cur[base + j] = v;
    }
}

__global__ void scatter_kernel(const int* __restrict__ src, const int* __restrict__ dst,
                               int* __restrict__ cur, int* __restrict__ edge_src) {
    int e = blockIdx.x * 256 + threadIdx.x;
    if (e < N_EDGES) {
        int d = dst[e];
        int slot = atomicAdd(&cur[d], 1);
        edge_src[slot] = src[e];
    }
}

// ---------------- Fused projection GEMM ----------------
// Grid (784, 2). Block computes 64 rows x 256 cols (two matrices x two 64-col
// halves), staging the A tile ONCE. q -> fp32, k/v -> packed bf16 kv buffer,
// s -> fp32 h. Optional fused BN+ReLU on the input load.
__global__ __launch_bounds__(256) void gemm_qkvs(
    const float* __restrict__ in,
    const float* __restrict__ Wq, const float* __restrict__ Wk,
    const float* __restrict__ Wv, const float* __restrict__ Ws,
    const float* __restrict__ bq, const float* __restrict__ bk,
    const float* __restrict__ bv, const float* __restrict__ bs,
    float* __restrict__ qb, unsigned short* __restrict__ kvb,
    float* __restrict__ hb,
    const float* __restrict__ bnA, const float* __restrict__ bnB)
{
    __shared__ float As[64][132];
    __shared__ float Bs[128][68];
    int t = threadIdx.x;
    int n0 = blockIdx.x * 64;
    int mbase = blockIdx.y * 2;

    // stage A once (with optional bn+relu)
    {
        int r  = t >> 5;          // 0..7
        int kq = (t & 31) * 4;    // 0..124
        float4 ba = make_float4(1.f, 1.f, 1.f, 1.f);
        float4 bb = make_float4(0.f, 0.f, 0.f, 0.f);
        if (bnA) {
            ba = *reinterpret_cast<const float4*>(&bnA[kq]);
            bb = *reinterpret_cast<const float4*>(&bnB[kq]);
        }
        #pragma unroll
        for (int p = 0; p < 8; p++) {
            int row = n0 + r + p * 8;
            float4 v = *reinterpret_cast<const float4*>(&in[(size_t)row * 128 + kq]);
            if (bnA) {
                v.x = fmaxf(v.x * ba.x + bb.x, 0.f);
                v.y = fmaxf(v.y * ba.y + bb.y, 0.f);
                v.z = fmaxf(v.z * ba.z + bb.z, 0.f);
                v.w = fmaxf(v.w * ba.w + bb.w, 0.f);
            }
            *reinterpret_cast<float4*>(&As[r + p * 8][kq]) = v;
        }
    }

    int ty = t >> 4, tx = t & 15;
    for (int sl = 0; sl < 4; ++sl) {
        int m = mbase + (sl >> 1);
        int cbase = (sl & 1) << 6;
        const float* W    = (m == 0) ? Wq : (m == 1) ? Wk : (m == 2) ? Wv : Ws;
        const float* bias = (m == 0) ? bq : (m == 1) ? bk : (m == 2) ? bv : bs;

        __syncthreads();   // A ready (sl=0) / previous slice done reading Bs
        {
            int kk = t >> 4;          // 0..15
            int cc = (t & 15) * 4;    // 0..60
            #pragma unroll
            for (int p = 0; p < 8; p++) {
                int k = kk + p * 16;
                float4 v = *reinterpret_cast<const float4*>(&W[k * 128 + cbase + cc]);
                *reinterpret_cast<float4*>(&Bs[k][cc]) = v;
            }
        }
        __syncthreads();

        float acc[4][4] = {};
        #pragma unroll 4
        for (int k4 = 0; k4 < 32; k4++) {
            float a[4][4], bvv[4][4];
            #pragma unroll
            for (int i = 0; i < 4; i++) {
                float4 av = *reinterpret_cast<const float4*>(&As[ty * 4 + i][k4 * 4]);
                a[i][0] = av.x; a[i][1] = av.y; a[i][2] = av.z; a[i][3] = av.w;
            }
            #pragma unroll
            for (int kk = 0; kk < 4; kk++) {
                float4 bv4 = *reinterpret_cast<const float4*>(&Bs[k4 * 4 + kk][tx * 4]);
                bvv[kk][0] = bv4.x; bvv[kk][1] = bv4.y; bvv[kk][2] = bv4.z; bvv[kk][3] = bv4.w;
            }
            #pragma unroll
            for (int kk = 0; kk < 4; kk++)
                #pragma unroll
                for (int i = 0; i < 4; i++)
                    #pragma unroll
                    for (int j = 0; j < 4; j++)
                        acc[i][j] += a[i][kk] * bvv[kk][j];
        }

        float4 bi = *reinterpret_cast<const float4*>(&bias[cbase + tx * 4]);
        #pragma unroll
        for (int i = 0; i < 4; i++) {
            int row = n0 + ty * 4 + i;
            float4 o;
            o.x = acc[i][0] + bi.x;
            o.y = acc[i][1] + bi.y;
            o.z = acc[i][2] + bi.z;
            o.w = acc[i][3] + bi.w;
            if (m == 0) {
                *reinterpret_cast<float4*>(&qb[(size_t)row * 128 + cbase + tx * 4]) = o;
            } else if (m == 3) {
                *reinterpret_cast<float4*>(&hb[(size_t)row * 128 + cbase + tx * 4]) = o;
            } else {
                ushort4 h;
                h.x = f2bf(o.x); h.y = f2bf(o.y); h.z = f2bf(o.z); h.w = f2bf(o.w);
                size_t koff = (m == 1) ? 0 : 128;
                *reinterpret_cast<ushort4*>(&kvb[(size_t)row * 256 + koff + cbase + tx * 4]) = h;
            }
        }
    }
}

// ---------------- Attention aggregation: 16 lanes/edge, 4 edges in flight ----
__global__ __launch_bounds__(256) void agg_kernel(
    const float* __restrict__ qb, const unsigned short* __restrict__ kvb,
    const int* __restrict__ row_ptr, const int* __restrict__ edge_src,
    float* __restrict__ hb)
{
    int wave = threadIdx.x >> 6, lane = threadIdx.x & 63;
    int n = blockIdx.x * 4 + wave;
    int quarter = lane >> 4, ql = lane & 15;

    float4 qa = *reinterpret_cast<const float4*>(&qb[(size_t)n * 128 + ql * 8]);
    float4 qc = *reinterpret_cast<const float4*>(&qb[(size_t)n * 128 + ql * 8 + 4]);
    int s0 = row_ptr[n], s1 = row_ptr[n + 1];

    float acc0 = 0.f, acc1 = 0.f, acc2 = 0.f, acc3 = 0.f;
    float acc4 = 0.f, acc5 = 0.f, acc6 = 0.f, acc7 = 0.f;
    float ssum = 0.f;

    for (int j0 = s0; j0 < s1; j0 += 4) {
        int j = j0 + quarter;
        bool act = (j < s1);
        int s = act ? edge_src[j] : 0;
        const uint4* kv4 = reinterpret_cast<const uint4*>(kvb + (size_t)s * 256);
        uint4 kr = kv4[ql];
        uint4 vr = kv4[16 + ql];

        float part = qa.x * bflo(kr.x) + qa.y * bfhi(kr.x)
                   + qa.z * bflo(kr.y) + qa.w * bfhi(kr.y)
                   + qc.x * bflo(kr.z) + qc.y * bfhi(kr.z)
                   + qc.z * bflo(kr.w) + qc.w * bfhi(kr.w);
        part += __shfl_xor(part, 1, 64);
        part += __shfl_xor(part, 2, 64);
        part += __shfl_xor(part, 4, 64);
        part += __shfl_xor(part, 8, 64);

        float w = act ? __expf(part * ATT_SCALE) : 0.f;
        ssum += w;
        acc0 += w * bflo(vr.x); acc1 += w * bfhi(vr.x);
        acc2 += w * bflo(vr.y); acc3 += w * bfhi(vr.y);
        acc4 += w * bflo(vr.z); acc5 += w * bfhi(vr.z);
        acc6 += w * bflo(vr.w); acc7 += w * bfhi(vr.w);
    }

    #define XRED(x) { x += __shfl_xor(x, 16, 64); x += __shfl_xor(x, 32, 64); }
    XRED(acc0) XRED(acc1) XRED(acc2) XRED(acc3)
    XRED(acc4) XRED(acc5) XRED(acc6) XRED(acc7)
    XRED(ssum)
    #undef XRED

    if (quarter == 0) {
        float inv = 1.0f / (ssum + 1e-16f);
        float4 h0 = *reinterpret_cast<float4*>(&hb[(size_t)n * 128 + ql * 8]);
        float4 h1 = *reinterpret_cast<float4*>(&hb[(size_t)n * 128 + ql * 8 + 4]);
        h0.x += acc0 * inv; h0.y += acc1 * inv; h0.z += acc2 * inv; h0.w += acc3 * inv;
        h1.x += acc4 * inv; h1.y += acc5 * inv; h1.z += acc6 * inv; h1.w += acc7 * inv;
        *reinterpret_cast<float4*>(&hb[(size_t)n * 128 + ql * 8]) = h0;
        *reinterpret_cast<float4*>(&hb[(size_t)n * 128 + ql * 8 + 4]) = h1;
    }
}

// ---------------- BatchNorm statistics ----------------
__global__ __launch_bounds__(256) void bn_stats(const float* __restrict__ h,
                                                float* __restrict__ sums,
                                                float* __restrict__ sqs) {
    int t = threadIdx.x;
    int c = t & 127;
    float s = 0.f, q = 0.f;
    int stride = gridDim.x * 256;
    for (int i = blockIdx.x * 256 + t; i < N_NODES * 128; i += stride) {
        float v = h[i];
        s += v; q += v * v;
    }
    __shared__ float sh[256], shq[256];
    sh[t] = s; shq[t] = q;
    __syncthreads();
    if (t < 128) {
        atomicAdd(&sums[c], sh[t] + sh[t + 128]);
        atomicAdd(&sqs[c],  shq[t] + shq[t + 128]);
    }
}

__global__ void bn_final(const float* __restrict__ sums, const float* __restrict__ sqs,
                         const float* __restrict__ g, const float* __restrict__ be,
                         float* __restrict__ a, float* __restrict__ b) {
    int c = threadIdx.x;
    float mean = sums[c] / (float)N_NODES;
    float var  = sqs[c] / (float)N_NODES - mean * mean;
    float inv  = rsqrtf(var + BN_EPS);
    float av   = g[c] * inv;
    a[c] = av;
    b[c] = be[c] - mean * av;
}

// ---------------- Final FC head: 8 nodes per 256-thread block ----------------
__global__ __launch_bounds__(256) void fc_kernel(
    const float* __restrict__ h2, const float* __restrict__ a1, const float* __restrict__ b1,
    const int* __restrict__ ptr, const float* __restrict__ gf,
    const float* __restrict__ fcW, const float* __restrict__ fcb,
    const float* __restrict__ fc2W, const float* __restrict__ fc2b,
    float* __restrict__ out)
{
    __shared__ float hc[8][144];
    __shared__ float red[8][128];
    int t = threadIdx.x;
    int nb = blockIdx.x * 8;

    // stage: 32 lanes per node
    {
        int node_l = t >> 5, li = t & 31;
        int n = nb + node_l;
        float4 v = *reinterpret_cast<const float4*>(&h2[(size_t)n * 128 + li * 4]);
        float4 av = *reinterpret_cast<const float4*>(&a1[li * 4]);
        float4 bv = *reinterpret_cast<const float4*>(&b1[li * 4]);
        hc[node_l][li * 4 + 0] = fmaxf(v.x * av.x + bv.x, 0.f);
        hc[node_l][li * 4 + 1] = fmaxf(v.y * av.y + bv.y, 0.f);
        hc[node_l][li * 4 + 2] = fmaxf(v.z * av.z + bv.z, 0.f);
        hc[node_l][li * 4 + 3] = fmaxf(v.w * av.w + bv.w, 0.f);
        if (li < 16) {
            int lo = 0, hi = NGRAPH;
            while (lo < hi) {
                int mid = (lo + hi + 1) >> 1;
                if (ptr[mid] <= n) lo = mid; else hi = mid - 1;
            }
            hc[node_l][128 + li] = gf[lo * 16 + li];
        }
    }
    __syncthreads();

    // FC1: each thread computes 1 output column for 4 nodes (fcW reuse x4)
    {
        int half = t >> 7, o = t & 127;
        float fb = fcb[o];
        float acc0 = fb, acc1 = fb, acc2 = fb, acc3 = fb;
        const float* h0 = hc[half * 4 + 0];
        const float* h1 = hc[half * 4 + 1];
        const float* h2c = hc[half * 4 + 2];
        const float* h3 = hc[half * 4 + 3];
        #pragma unroll 16
        for (int i = 0; i < 144; i++) {
            float w = fcW[i * 128 + o];
            acc0 += h0[i] * w;
            acc1 += h1[i] * w;
            acc2 += h2c[i] * w;
            acc3 += h3[i] * w;
        }
        float w2 = fc2W[o];
        red[half * 4 + 0][o] = fmaxf(acc0, 0.f) * w2;
        red[half * 4 + 1][o] = fmaxf(acc1, 0.f) * w2;
        red[half * 4 + 2][o] = fmaxf(acc2, 0.f) * w2;
        red[half * 4 + 3][o] = fmaxf(acc3, 0.f) * w2;
    }
    __syncthreads();

    // FC2 reduce: 32 lanes per node
    {
        int node_l = t >> 5, li = t & 31;
        float s = red[node_l][li] + red[node_l][li + 32]
                + red[node_l][li + 64] + red[node_l][li + 96];
        s += __shfl_xor(s, 1, 64);
        s += __shfl_xor(s, 2, 64);
        s += __shfl_xor(s, 4, 64);
        s += __shfl_xor(s, 8, 64);
        s += __shfl_xor(s, 16, 64);
        if (li == 0) out[nb + node_l] = s + fc2b[0];
    }
}

// ---------------- launch ----------------
extern "C" void kernel_launch(void* const* d_in, const int* in_sizes, int n_in,
                              void* d_out, int out_size, void* d_ws, size_t ws_size,
                              hipStream_t stream)
{
    const float* x   = (const float*)d_in[0];
    const int*   ei  = (const int*)d_in[1];
    const int*   ptr = (const int*)d_in[2];
    const float* gf  = (const float*)d_in[3];
    const float* Wq0 = (const float*)d_in[4];
    const float* Wk0 = (const float*)d_in[5];
    const float* Wv0 = (const float*)d_in[6];
    const float* Ws0 = (const float*)d_in[7];
    const float* bq0 = (const float*)d_in[8];
    const float* bk0 = (const float*)d_in[9];
    const float* bv0 = (const float*)d_in[10];
    const float* bs0 = (const float*)d_in[11];
    const float* g0  = (const float*)d_in[12];
    const float* be0 = (const float*)d_in[13];
    const float* Wq1 = (const float*)d_in[14];
    const float* Wk1 = (const float*)d_in[15];
    const float* Wv1 = (const float*)d_in[16];
    const float* Ws1 = (const float*)d_in[17];
    const float* bq1 = (const float*)d_in[18];
    const float* bk1 = (const float*)d_in[19];
    const float* bv1 = (const float*)d_in[20];
    const float* bs1 = (const float*)d_in[21];
    const float* g1  = (const float*)d_in[22];
    const float* be1 = (const float*)d_in[23];
    const float* fcW = (const float*)d_in[24];
    const float* fcb = (const float*)d_in[25];
    const float* fc2W= (const float*)d_in[26];
    const float* fc2b= (const float*)d_in[27];
    float* out = (float*)d_out;

    const int* src_p = ei;
    const int* dst_p = ei + N_EDGES;

    char* w = (char*)d_ws;
    const size_t NM = (size_t)N_NODES * 128 * sizeof(float);
    float* qb = (float*)w;                 w += NM;
    unsigned short* kvb = (unsigned short*)w; w += (size_t)N_NODES * 256 * sizeof(unsigned short);
    float* h1 = (float*)w;                 w += NM;
    float* h2 = (float*)w;                 w += NM;
    float* stats = (float*)w;              w += 1024 * sizeof(float);
    float* sums0 = stats;
    float* sqs0  = stats + 128;
    float* sums1 = stats + 256;
    float* sqs1  = stats + 384;
    float* a0    = stats + 512;
    float* b0    = stats + 640;
    float* a1    = stats + 768;
    float* b1    = stats + 896;
    int* cnt     = (int*)w;                w += (size_t)N_NODES * sizeof(int);
    int* row_ptr = (int*)w;                w += (size_t)(N_NODES + 1) * sizeof(int);
    int* cur     = (int*)w;                w += (size_t)N_NODES * sizeof(int);
    int* edge_src= (int*)w;                w += (size_t)N_EDGES * sizeof(int);
    int* bsum    = (int*)w;                w += 64 * sizeof(int);
    int* boff    = (int*)w;                w += 64 * sizeof(int);

    hipMemsetAsync(cnt, 0, (size_t)N_NODES * sizeof(int), stream);
    hipMemsetAsync(stats, 0, 512 * sizeof(float), stream);

    // CSR build (reused by both layers)
    hist_kernel<<<3136, 256, 0, stream>>>(dst_p, cnt);
    scan1_kernel<<<49, 256, 0, stream>>>(cnt, row_ptr, bsum);
    scan2_kernel<<<1, 1, 0, stream>>>(bsum, boff, row_ptr);
    scan3_kernel<<<49, 256, 0, stream>>>(row_ptr, cur, boff);
    scatter_kernel<<<3136, 256, 0, stream>>>(src_p, dst_p, cur, edge_src);

    // Layer 0
    gemm_qkvs<<<dim3(784, 2), 256, 0, stream>>>(x, Wq0, Wk0, Wv0, Ws0,
        bq0, bk0, bv0, bs0, qb, kvb, h1, nullptr, nullptr);
    agg_kernel<<<12544, 256, 0, stream>>>(qb, kvb, row_ptr, edge_src, h1);
    bn_stats<<<784, 256, 0, stream>>>(h1, sums0, sqs0);
    bn_final<<<1, 128, 0, stream>>>(sums0, sqs0, g0, be0, a0, b0);

    // Layer 1 (BN+ReLU fused into GEMM input load)
    gemm_qkvs<<<dim3(784, 2), 256, 0, stream>>>(h1, Wq1, Wk1, Wv1, Ws1,
        bq1, bk1, bv1, bs1, qb, kvb, h2, a0, b0);
    agg_kernel<<<12544, 256, 0, stream>>>(qb, kvb, row_ptr, edge_src, h2);
    bn_stats<<<784, 256, 0, stream>>>(h2, sums1, sqs1);
    bn_final<<<1, 128, 0, stream>>>(sums1, sqs1, g1, be1, a1, b1);

    // Head
    fc_kernel<<<6272, 256, 0, stream>>>(h2, a1, b1, ptr, gf,
        fcW, fcb, fc2W, fc2b, out);
}

// Round 3
// 561.267 us; speedup vs baseline: 1.5363x; 1.1519x over previous
//
#include <hip/hip_runtime.h>
#include <math.h>

#define N_NODES 50176
#define N_EDGES 802816
#define HIDDEN  128
#define NGRAPH  64
#define BN_EPS  1e-5f
#define ATT_SCALE 0.08838834764831845f  // 1/sqrt(128)

typedef __attribute__((ext_vector_type(8))) short bf16x8;
typedef __attribute__((ext_vector_type(4))) float f32x4;

__device__ __forceinline__ float bflo(unsigned u) { return __uint_as_float(u << 16); }
__device__ __forceinline__ float bfhi(unsigned u) { return __uint_as_float(u & 0xffff0000u); }
__device__ __forceinline__ unsigned short f2bf(float f) {
    unsigned u = __float_as_uint(f);
    unsigned r = (u + 0x7fffu + ((u >> 16) & 1u)) >> 16;
    return (unsigned short)r;
}

// ---------------- CSR build ----------------
__global__ void hist_kernel(const int* __restrict__ dst, int* __restrict__ cnt) {
    int e = blockIdx.x * 256 + threadIdx.x;
    if (e < N_EDGES) atomicAdd(&cnt[dst[e]], 1);
}

__global__ void scan1_kernel(const int* __restrict__ cnt, int* __restrict__ row_ptr,
                             int* __restrict__ bsum) {
    __shared__ int sh[256];
    int t = threadIdx.x, b = blockIdx.x;
    int base = b * 1024 + t * 4;
    int v0 = cnt[base], v1 = cnt[base + 1], v2 = cnt[base + 2], v3 = cnt[base + 3];
    int tot = v0 + v1 + v2 + v3;
    sh[t] = tot; __syncthreads();
    for (int off = 1; off < 256; off <<= 1) {
        int x = (t >= off) ? sh[t - off] : 0;
        __syncthreads();
        sh[t] += x;
        __syncthreads();
    }
    int excl = sh[t] - tot;
    row_ptr[base]     = excl;
    row_ptr[base + 1] = excl + v0;
    row_ptr[base + 2] = excl + v0 + v1;
    row_ptr[base + 3] = excl + v0 + v1 + v2;
    if (t == 255) bsum[b] = sh[255];
}

__global__ void scan2_kernel(const int* __restrict__ bsum, int* __restrict__ boff,
                             int* __restrict__ row_ptr) {
    int acc = 0;
    for (int i = 0; i < 49; i++) { boff[i] = acc; acc += bsum[i]; }
    row_ptr[N_NODES] = acc;
}

__global__ void scan3_kernel(int* __restrict__ row_ptr, int* __restrict__ cur,
                             const int* __restrict__ boff) {
    int t = threadIdx.x, b = blockIdx.x;
    int base = b * 1024 + t * 4;
    int off = boff[b];
    #pragma unroll
    for (int j = 0; j < 4; j++) {
        int v = row_ptr[base + j] + off;
        row_ptr[base + j] = v;
        cur[base + j] = v;
    }
}

__global__ void scatter_kernel(const int* __restrict__ src, const int* __restrict__ dst,
                               int* __restrict__ cur, int* __restrict__ edge_src) {
    int e = blockIdx.x * 256 + threadIdx.x;
    if (e < N_EDGES) {
        int d = dst[e];
        int slot = atomicAdd(&cur[d], 1);
        edge_src[slot] = src[e];
    }
}

// ---------------- Weight prep: f32 [128k][128c] -> bf16 WT [mat][c][k] ------
__global__ void wprep_kernel(const float* __restrict__ Wq, const float* __restrict__ Wk,
                             const float* __restrict__ Wv, const float* __restrict__ Ws,
                             unsigned short* __restrict__ WT) {
    int mb = blockIdx.x;
    const float* W = (mb == 0) ? Wq : (mb == 1) ? Wk : (mb == 2) ? Wv : Ws;
    int t = threadIdx.x;
    int k = t >> 1, ch = t & 1;
    #pragma unroll 8
    for (int cc = 0; cc < 64; cc++) {
        int c = ch * 64 + cc;
        WT[((size_t)mb * 128 + c) * 128 + k] = f2bf(W[k * 128 + c]);
    }
}

// ---------------- MFMA projection GEMM -------------------------------------
// Grid (392, 4): block = 128 rows x 128 cols (matrix m = blockIdx.y).
// A (fp32, optional BN+ReLU) -> bf16 LDS (XOR-swizzled); B from pre-transposed
// bf16 WT -> LDS. 4 waves (2x2), each 64x64 via 4x4 frags x 4 k-steps.
__global__ __launch_bounds__(256) void gemm_mfma(
    const float* __restrict__ in,
    const unsigned short* __restrict__ WT,
    const float* __restrict__ bq, const float* __restrict__ bk,
    const float* __restrict__ bv, const float* __restrict__ bs,
    float* __restrict__ qb, unsigned short* __restrict__ kvb,
    float* __restrict__ hb,
    const float* __restrict__ bnA, const float* __restrict__ bnB)
{
    __shared__ unsigned char lds[65536];   // As [0,32K), Bs [32K,64K)
    int t = threadIdx.x;
    int n0 = blockIdx.x * 128;
    int m  = blockIdx.y;

    // ---- stage A: fp32 -> bf16, swizzled ----
    {
        int r = t >> 1, seg = t & 1;
        const float* srcp = in + (size_t)(n0 + r) * 128 + seg * 64;
        unsigned rowbase = r * 256;
        unsigned sw = (r & 7) << 4;
        #pragma unroll
        for (int c = 0; c < 8; c++) {
            float4 f0 = *reinterpret_cast<const float4*>(srcp + c * 8);
            float4 f1 = *reinterpret_cast<const float4*>(srcp + c * 8 + 4);
            if (bnA) {
                int kb = seg * 64 + c * 8;
                float4 a0 = *reinterpret_cast<const float4*>(&bnA[kb]);
                float4 a1 = *reinterpret_cast<const float4*>(&bnA[kb + 4]);
                float4 b0 = *reinterpret_cast<const float4*>(&bnB[kb]);
                float4 b1 = *reinterpret_cast<const float4*>(&bnB[kb + 4]);
                f0.x = fmaxf(f0.x * a0.x + b0.x, 0.f);
                f0.y = fmaxf(f0.y * a0.y + b0.y, 0.f);
                f0.z = fmaxf(f0.z * a0.z + b0.z, 0.f);
                f0.w = fmaxf(f0.w * a0.w + b0.w, 0.f);
                f1.x = fmaxf(f1.x * a1.x + b1.x, 0.f);
                f1.y = fmaxf(f1.y * a1.y + b1.y, 0.f);
                f1.z = fmaxf(f1.z * a1.z + b1.z, 0.f);
                f1.w = fmaxf(f1.w * a1.w + b1.w, 0.f);
            }
            uint4 pk;
            pk.x = (unsigned)f2bf(f0.x) | ((unsigned)f2bf(f0.y) << 16);
            pk.y = (unsigned)f2bf(f0.z) | ((unsigned)f2bf(f0.w) << 16);
            pk.z = (unsigned)f2bf(f1.x) | ((unsigned)f2bf(f1.y) << 16);
            pk.w = (unsigned)f2bf(f1.z) | ((unsigned)f2bf(f1.w) << 16);
            unsigned off = (unsigned)(seg * 128 + c * 16);
            *reinterpret_cast<uint4*>(&lds[rowbase + (off ^ sw)]) = pk;
        }
    }
    // ---- stage B: bf16 WT rows (already [col][k]) -> LDS, swizzled ----
    {
        int r = t >> 1, seg = t & 1;
        const unsigned short* srcp = WT + ((size_t)m * 128 + r) * 128 + seg * 64;
        unsigned rowbase = 32768u + r * 256;
        unsigned sw = (r & 7) << 4;
        #pragma unroll
        for (int c = 0; c < 8; c++) {
            uint4 pk = *reinterpret_cast<const uint4*>(srcp + c * 8);
            unsigned off = (unsigned)(seg * 128 + c * 16);
            *reinterpret_cast<uint4*>(&lds[rowbase + (off ^ sw)]) = pk;
        }
    }
    __syncthreads();

    int lane = t & 63, w = t >> 6;
    int wr = w >> 1, wc = w & 1;
    int lrow = lane & 15, lk = lane >> 4;      // lk in 0..3
    unsigned sw = (unsigned)((lrow & 7) << 4);

    f32x4 acc[4][4] = {};
    #pragma unroll
    for (int ks = 0; ks < 4; ks++) {
        unsigned o = (unsigned)(ks * 64 + lk * 16);
        bf16x8 af[4], bfr[4];
        #pragma unroll
        for (int i = 0; i < 4; i++) {
            unsigned row = wr * 64 + i * 16 + lrow;
            af[i] = *reinterpret_cast<const bf16x8*>(&lds[row * 256 + (o ^ sw)]);
            unsigned col = wc * 64 + i * 16 + lrow;
            bfr[i] = *reinterpret_cast<const bf16x8*>(&lds[32768u + col * 256 + (o ^ sw)]);
        }
        #pragma unroll
        for (int i = 0; i < 4; i++)
            #pragma unroll
            for (int j = 0; j < 4; j++)
                acc[i][j] = __builtin_amdgcn_mfma_f32_16x16x32_bf16(af[i], bfr[j], acc[i][j], 0, 0, 0);
    }

    // ---- epilogue: bias + route ----
    const float* bias = (m == 0) ? bq : (m == 1) ? bk : (m == 2) ? bv : bs;
    #pragma unroll
    for (int j = 0; j < 4; j++) {
        int c = wc * 64 + j * 16 + lrow;
        float bi = bias[c];
        #pragma unroll
        for (int i = 0; i < 4; i++) {
            #pragma unroll
            for (int r = 0; r < 4; r++) {
                int row = n0 + wr * 64 + i * 16 + lk * 4 + r;
                float v = acc[i][j][r] + bi;
                if (m == 0) {
                    qb[(size_t)row * 128 + c] = v;
                } else if (m == 3) {
                    hb[(size_t)row * 128 + c] = v;
                } else {
                    kvb[(size_t)row * 256 + (m == 1 ? 0 : 128) + c] = f2bf(v);
                }
            }
        }
    }
}

// ---------------- Attention aggregation: 16 lanes/edge, 4 edges in flight ----
__global__ __launch_bounds__(256) void agg_kernel(
    const float* __restrict__ qb, const unsigned short* __restrict__ kvb,
    const int* __restrict__ row_ptr, const int* __restrict__ edge_src,
    float* __restrict__ hb)
{
    int wave = threadIdx.x >> 6, lane = threadIdx.x & 63;
    int n = blockIdx.x * 4 + wave;
    int quarter = lane >> 4, ql = lane & 15;

    float4 qa = *reinterpret_cast<const float4*>(&qb[(size_t)n * 128 + ql * 8]);
    float4 qc = *reinterpret_cast<const float4*>(&qb[(size_t)n * 128 + ql * 8 + 4]);
    int s0 = row_ptr[n], s1 = row_ptr[n + 1];

    float acc0 = 0.f, acc1 = 0.f, acc2 = 0.f, acc3 = 0.f;
    float acc4 = 0.f, acc5 = 0.f, acc6 = 0.f, acc7 = 0.f;
    float ssum = 0.f;

    for (int j0 = s0; j0 < s1; j0 += 4) {
        int j = j0 + quarter;
        bool act = (j < s1);
        int s = act ? edge_src[j] : 0;
        const uint4* kv4 = reinterpret_cast<const uint4*>(kvb + (size_t)s * 256);
        uint4 kr = kv4[ql];
        uint4 vr = kv4[16 + ql];

        float part = qa.x * bflo(kr.x) + qa.y * bfhi(kr.x)
                   + qa.z * bflo(kr.y) + qa.w * bfhi(kr.y)
                   + qc.x * bflo(kr.z) + qc.y * bfhi(kr.z)
                   + qc.z * bflo(kr.w) + qc.w * bfhi(kr.w);
        part += __shfl_xor(part, 1, 64);
        part += __shfl_xor(part, 2, 64);
        part += __shfl_xor(part, 4, 64);
        part += __shfl_xor(part, 8, 64);

        float wgt = act ? __expf(part * ATT_SCALE) : 0.f;
        ssum += wgt;
        acc0 += wgt * bflo(vr.x); acc1 += wgt * bfhi(vr.x);
        acc2 += wgt * bflo(vr.y); acc3 += wgt * bfhi(vr.y);
        acc4 += wgt * bflo(vr.z); acc5 += wgt * bfhi(vr.z);
        acc6 += wgt * bflo(vr.w); acc7 += wgt * bfhi(vr.w);
    }

    #define XRED(x) { x += __shfl_xor(x, 16, 64); x += __shfl_xor(x, 32, 64); }
    XRED(acc0) XRED(acc1) XRED(acc2) XRED(acc3)
    XRED(acc4) XRED(acc5) XRED(acc6) XRED(acc7)
    XRED(ssum)
    #undef XRED

    if (quarter == 0) {
        float inv = 1.0f / (ssum + 1e-16f);
        float4 h0 = *reinterpret_cast<float4*>(&hb[(size_t)n * 128 + ql * 8]);
        float4 h1 = *reinterpret_cast<float4*>(&hb[(size_t)n * 128 + ql * 8 + 4]);
        h0.x += acc0 * inv; h0.y += acc1 * inv; h0.z += acc2 * inv; h0.w += acc3 * inv;
        h1.x += acc4 * inv; h1.y += acc5 * inv; h1.z += acc6 * inv; h1.w += acc7 * inv;
        *reinterpret_cast<float4*>(&hb[(size_t)n * 128 + ql * 8]) = h0;
        *reinterpret_cast<float4*>(&hb[(size_t)n * 128 + ql * 8 + 4]) = h1;
    }
}

// ---------------- BatchNorm statistics ----------------
__global__ __launch_bounds__(256) void bn_stats(const float* __restrict__ h,
                                                float* __restrict__ sums,
                                                float* __restrict__ sqs) {
    int t = threadIdx.x;
    int c = t & 127;
    float s = 0.f, q = 0.f;
    int stride = gridDim.x * 256;
    for (int i = blockIdx.x * 256 + t; i < N_NODES * 128; i += stride) {
        float v = h[i];
        s += v; q += v * v;
    }
    __shared__ float sh[256], shq[256];
    sh[t] = s; shq[t] = q;
    __syncthreads();
    if (t < 128) {
        atomicAdd(&sums[c], sh[t] + sh[t + 128]);
        atomicAdd(&sqs[c],  shq[t] + shq[t + 128]);
    }
}

__global__ void bn_final(const float* __restrict__ sums, const float* __restrict__ sqs,
                         const float* __restrict__ g, const float* __restrict__ be,
                         float* __restrict__ a, float* __restrict__ b) {
    int c = threadIdx.x;
    float mean = sums[c] / (float)N_NODES;
    float var  = sqs[c] / (float)N_NODES - mean * mean;
    float inv  = rsqrtf(var + BN_EPS);
    float av   = g[c] * inv;
    a[c] = av;
    b[c] = be[c] - mean * av;
}

// ---------------- Final FC head: 8 nodes per 256-thread block ----------------
__global__ __launch_bounds__(256) void fc_kernel(
    const float* __restrict__ h2, const float* __restrict__ a1, const float* __restrict__ b1,
    const int* __restrict__ ptr, const float* __restrict__ gf,
    const float* __restrict__ fcW, const float* __restrict__ fcb,
    const float* __restrict__ fc2W, const float* __restrict__ fc2b,
    float* __restrict__ out)
{
    __shared__ float hc[8][144];
    __shared__ float red[8][128];
    int t = threadIdx.x;
    int nb = blockIdx.x * 8;

    {
        int node_l = t >> 5, li = t & 31;
        int n = nb + node_l;
        float4 v = *reinterpret_cast<const float4*>(&h2[(size_t)n * 128 + li * 4]);
        float4 av = *reinterpret_cast<const float4*>(&a1[li * 4]);
        float4 bv = *reinterpret_cast<const float4*>(&b1[li * 4]);
        hc[node_l][li * 4 + 0] = fmaxf(v.x * av.x + bv.x, 0.f);
        hc[node_l][li * 4 + 1] = fmaxf(v.y * av.y + bv.y, 0.f);
        hc[node_l][li * 4 + 2] = fmaxf(v.z * av.z + bv.z, 0.f);
        hc[node_l][li * 4 + 3] = fmaxf(v.w * av.w + bv.w, 0.f);
        if (li < 16) {
            int lo = 0, hi = NGRAPH;
            while (lo < hi) {
                int mid = (lo + hi + 1) >> 1;
                if (ptr[mid] <= n) lo = mid; else hi = mid - 1;
            }
            hc[node_l][128 + li] = gf[lo * 16 + li];
        }
    }
    __syncthreads();

    {
        int half = t >> 7, o = t & 127;
        float fb = fcb[o];
        float acc0 = fb, acc1 = fb, acc2 = fb, acc3 = fb;
        const float* h0 = hc[half * 4 + 0];
        const float* h1 = hc[half * 4 + 1];
        const float* h2c = hc[half * 4 + 2];
        const float* h3 = hc[half * 4 + 3];
        #pragma unroll 16
        for (int i = 0; i < 144; i++) {
            float w = fcW[i * 128 + o];
            acc0 += h0[i] * w;
            acc1 += h1[i] * w;
            acc2 += h2c[i] * w;
            acc3 += h3[i] * w;
        }
        float w2 = fc2W[o];
        red[half * 4 + 0][o] = fmaxf(acc0, 0.f) * w2;
        red[half * 4 + 1][o] = fmaxf(acc1, 0.f) * w2;
        red[half * 4 + 2][o] = fmaxf(acc2, 0.f) * w2;
        red[half * 4 + 3][o] = fmaxf(acc3, 0.f) * w2;
    }
    __syncthreads();

    {
        int node_l = t >> 5, li = t & 31;
        float s = red[node_l][li] + red[node_l][li + 32]
                + red[node_l][li + 64] + red[node_l][li + 96];
        s += __shfl_xor(s, 1, 64);
        s += __shfl_xor(s, 2, 64);
        s += __shfl_xor(s, 4, 64);
        s += __shfl_xor(s, 8, 64);
        s += __shfl_xor(s, 16, 64);
        if (li == 0) out[nb + node_l] = s + fc2b[0];
    }
}

// ---------------- launch ----------------
extern "C" void kernel_launch(void* const* d_in, const int* in_sizes, int n_in,
                              void* d_out, int out_size, void* d_ws, size_t ws_size,
                              hipStream_t stream)
{
    const float* x   = (const float*)d_in[0];
    const int*   ei  = (const int*)d_in[1];
    const int*   ptr = (const int*)d_in[2];
    const float* gf  = (const float*)d_in[3];
    const float* Wq0 = (const float*)d_in[4];
    const float* Wk0 = (const float*)d_in[5];
    const float* Wv0 = (const float*)d_in[6];
    const float* Ws0 = (const float*)d_in[7];
    const float* bq0 = (const float*)d_in[8];
    const float* bk0 = (const float*)d_in[9];
    const float* bv0 = (const float*)d_in[10];
    const float* bs0 = (const float*)d_in[11];
    const float* g0  = (const float*)d_in[12];
    const float* be0 = (const float*)d_in[13];
    const float* Wq1 = (const float*)d_in[14];
    const float* Wk1 = (const float*)d_in[15];
    const float* Wv1 = (const float*)d_in[16];
    const float* Ws1 = (const float*)d_in[17];
    const float* bq1 = (const float*)d_in[18];
    const float* bk1 = (const float*)d_in[19];
    const float* bv1 = (const float*)d_in[20];
    const float* bs1 = (const float*)d_in[21];
    const float* g1  = (const float*)d_in[22];
    const float* be1 = (const float*)d_in[23];
    const float* fcW = (const float*)d_in[24];
    const float* fcb = (const float*)d_in[25];
    const float* fc2W= (const float*)d_in[26];
    const float* fc2b= (const float*)d_in[27];
    float* out = (float*)d_out;

    const int* src_p = ei;
    const int* dst_p = ei + N_EDGES;

    char* w = (char*)d_ws;
    const size_t NM = (size_t)N_NODES * 128 * sizeof(float);
    float* qb = (float*)w;                    w += NM;
    unsigned short* kvb = (unsigned short*)w; w += (size_t)N_NODES * 256 * sizeof(unsigned short);
    float* h1 = (float*)w;                    w += NM;
    float* h2 = (float*)w;                    w += NM;
    float* stats = (float*)w;                 w += 1024 * sizeof(float);
    float* sums0 = stats;
    float* sqs0  = stats + 128;
    float* sums1 = stats + 256;
    float* sqs1  = stats + 384;
    float* a0    = stats + 512;
    float* b0    = stats + 640;
    float* a1    = stats + 768;
    float* b1    = stats + 896;
    unsigned short* WT0 = (unsigned short*)w; w += (size_t)512 * 128 * sizeof(unsigned short);
    unsigned short* WT1 = (unsigned short*)w; w += (size_t)512 * 128 * sizeof(unsigned short);
    int* cnt     = (int*)w;                   w += (size_t)N_NODES * sizeof(int);
    int* row_ptr = (int*)w;                   w += (size_t)(N_NODES + 1) * sizeof(int);
    int* cur     = (int*)w;                   w += (size_t)N_NODES * sizeof(int);
    int* edge_src= (int*)w;                   w += (size_t)N_EDGES * sizeof(int);
    int* bsum    = (int*)w;                   w += 64 * sizeof(int);
    int* boff    = (int*)w;                   w += 64 * sizeof(int);

    hipMemsetAsync(cnt, 0, (size_t)N_NODES * sizeof(int), stream);
    hipMemsetAsync(stats, 0, 512 * sizeof(float), stream);

    // Weight prep (both layers)
    wprep_kernel<<<4, 256, 0, stream>>>(Wq0, Wk0, Wv0, Ws0, WT0);
    wprep_kernel<<<4, 256, 0, stream>>>(Wq1, Wk1, Wv1, Ws1, WT1);

    // CSR build (reused by both layers)
    hist_kernel<<<3136, 256, 0, stream>>>(dst_p, cnt);
    scan1_kernel<<<49, 256, 0, stream>>>(cnt, row_ptr, bsum);
    scan2_kernel<<<1, 1, 0, stream>>>(bsum, boff, row_ptr);
    scan3_kernel<<<49, 256, 0, stream>>>(row_ptr, cur, boff);
    scatter_kernel<<<3136, 256, 0, stream>>>(src_p, dst_p, cur, edge_src);

    // Layer 0
    gemm_mfma<<<dim3(392, 4), 256, 0, stream>>>(x, WT0,
        bq0, bk0, bv0, bs0, qb, kvb, h1, nullptr, nullptr);
    agg_kernel<<<12544, 256, 0, stream>>>(qb, kvb, row_ptr, edge_src, h1);
    bn_stats<<<784, 256, 0, stream>>>(h1, sums0, sqs0);
    bn_final<<<1, 128, 0, stream>>>(sums0, sqs0, g0, be0, a0, b0);

    // Layer 1 (BN+ReLU fused into GEMM A-staging)
    gemm_mfma<<<dim3(392, 4), 256, 0, stream>>>(h1, WT1,
        bq1, bk1, bv1, bs1, qb, kvb, h2, a0, b0);
    agg_kernel<<<12544, 256, 0, stream>>>(qb, kvb, row_ptr, edge_src, h2);
    bn_stats<<<784, 256, 0, stream>>>(h2, sums1, sqs1);
    bn_final<<<1, 128, 0, stream>>>(sums1, sqs1, g1, be1, a1, b1);

    // Head
    fc_kernel<<<6272, 256, 0, stream>>>(h2, a1, b1, ptr, gf,
        fcW, fcb, fc2W, fc2b, out);
}

// Round 5
// 519.427 us; speedup vs baseline: 1.6600x; 1.0806x over previous
//
#include <hip/hip_runtime.h>
#include <math.h>

#define N_NODES 50176
#define N_EDGES 802816
#define HIDDEN  128
#define NGRAPH  64
#define BN_EPS  1e-5f
#define ATT_SCALE 0.08838834764831845f  // 1/sqrt(128)

typedef __attribute__((ext_vector_type(8))) short bf16x8;
typedef __attribute__((ext_vector_type(4))) float f32x4;

__device__ __forceinline__ float bflo(unsigned u) { return __uint_as_float(u << 16); }
__device__ __forceinline__ float bfhi(unsigned u) { return __uint_as_float(u & 0xffff0000u); }
__device__ __forceinline__ unsigned short f2bf(float f) {
    unsigned u = __float_as_uint(f);
    unsigned r = (u + 0x7fffu + ((u >> 16) & 1u)) >> 16;
    return (unsigned short)r;
}

// ---------------- CSR build ----------------
__global__ void hist_kernel(const int* __restrict__ dst, int* __restrict__ cnt) {
    int e = blockIdx.x * 256 + threadIdx.x;
    if (e < N_EDGES) atomicAdd(&cnt[dst[e]], 1);
}

__global__ void scan1_kernel(const int* __restrict__ cnt, int* __restrict__ row_ptr,
                             int* __restrict__ bsum) {
    __shared__ int sh[256];
    int t = threadIdx.x, b = blockIdx.x;
    int base = b * 1024 + t * 4;
    int v0 = cnt[base], v1 = cnt[base + 1], v2 = cnt[base + 2], v3 = cnt[base + 3];
    int tot = v0 + v1 + v2 + v3;
    sh[t] = tot; __syncthreads();
    for (int off = 1; off < 256; off <<= 1) {
        int x = (t >= off) ? sh[t - off] : 0;
        __syncthreads();
        sh[t] += x;
        __syncthreads();
    }
    int excl = sh[t] - tot;
    row_ptr[base]     = excl;
    row_ptr[base + 1] = excl + v0;
    row_ptr[base + 2] = excl + v0 + v1;
    row_ptr[base + 3] = excl + v0 + v1 + v2;
    if (t == 255) bsum[b] = sh[255];
}

__global__ void scan2_kernel(const int* __restrict__ bsum, int* __restrict__ boff,
                             int* __restrict__ row_ptr) {
    int acc = 0;
    for (int i = 0; i < 49; i++) { boff[i] = acc; acc += bsum[i]; }
    row_ptr[N_NODES] = acc;
}

__global__ void scan3_kernel(int* __restrict__ row_ptr, int* __restrict__ cur,
                             const int* __restrict__ boff) {
    int t = threadIdx.x, b = blockIdx.x;
    int base = b * 1024 + t * 4;
    int off = boff[b];
    #pragma unroll
    for (int j = 0; j < 4; j++) {
        int v = row_ptr[base + j] + off;
        row_ptr[base + j] = v;
        cur[base + j] = v;
    }
}

__global__ void scatter_kernel(const int* __restrict__ src, const int* __restrict__ dst,
                               int* __restrict__ cur, int* __restrict__ edge_src) {
    int e = blockIdx.x * 256 + threadIdx.x;
    if (e < N_EDGES) {
        int d = dst[e];
        int slot = atomicAdd(&cur[d], 1);
        edge_src[slot] = src[e];
    }
}

// ---------------- Weight prep: f32 [128k][128c] -> bf16 WT [mat][c][k] ------
__global__ void wprep_kernel(const float* __restrict__ Wq, const float* __restrict__ Wk,
                             const float* __restrict__ Wv, const float* __restrict__ Ws,
                             unsigned short* __restrict__ WT) {
    int mb = blockIdx.x;
    const float* W = (mb == 0) ? Wq : (mb == 1) ? Wk : (mb == 2) ? Wv : Ws;
    int t = threadIdx.x;
    int k = t >> 1, ch = t & 1;
    #pragma unroll 8
    for (int cc = 0; cc < 64; cc++) {
        int c = ch * 64 + cc;
        WT[((size_t)mb * 128 + c) * 128 + k] = f2bf(W[k * 128 + c]);
    }
}

// ---------------- MFMA projection GEMM (single pass over A) -----------------
// Grid 784, block 512 (8 waves). Block tile = 64 rows x 512 cols.
// Wave w: matrix m = w>>1, col half = w&1 (64 cols). A staged ONCE in LDS
// (bf16, swizzled). B read per-wave from pre-transposed WT (L2-resident).
// k/v outputs staged through swizzled LDS so kvb rows are 512B coalesced.
__global__ __launch_bounds__(512, 4) void gemm_mfma(
    const float* __restrict__ in,
    const unsigned short* __restrict__ WT,
    const float* __restrict__ bq, const float* __restrict__ bk,
    const float* __restrict__ bv, const float* __restrict__ bs,
    float* __restrict__ qb, unsigned short* __restrict__ kvb,
    float* __restrict__ hb,
    const float* __restrict__ bnA, const float* __restrict__ bnB)
{
    __shared__ unsigned char ldsA[16384];    // 64 rows x 256B (128 bf16), swizzled
    __shared__ unsigned char ldsKV[32768];   // 64 rows x 512B (k|v ushorts), swizzled
    int t = threadIdx.x;
    int n0 = blockIdx.x * 64;

    // ---- stage A once: fp32 (+opt BN/ReLU) -> bf16 LDS ----
    {
        int r = t >> 3, seg = t & 7;         // 8 threads/row, 16 floats each
        const float* srcp = in + (size_t)(n0 + r) * 128 + seg * 16;
        float4 f0 = *reinterpret_cast<const float4*>(srcp);
        float4 f1 = *reinterpret_cast<const float4*>(srcp + 4);
        float4 f2 = *reinterpret_cast<const float4*>(srcp + 8);
        float4 f3 = *reinterpret_cast<const float4*>(srcp + 12);
        if (bnA) {
            int kb = seg * 16;
            float4 a0 = *reinterpret_cast<const float4*>(&bnA[kb]);
            float4 a1 = *reinterpret_cast<const float4*>(&bnA[kb + 4]);
            float4 a2 = *reinterpret_cast<const float4*>(&bnA[kb + 8]);
            float4 a3 = *reinterpret_cast<const float4*>(&bnA[kb + 12]);
            float4 b0 = *reinterpret_cast<const float4*>(&bnB[kb]);
            float4 b1 = *reinterpret_cast<const float4*>(&bnB[kb + 4]);
            float4 b2 = *reinterpret_cast<const float4*>(&bnB[kb + 8]);
            float4 b3 = *reinterpret_cast<const float4*>(&bnB[kb + 12]);
            f0.x = fmaxf(f0.x * a0.x + b0.x, 0.f); f0.y = fmaxf(f0.y * a0.y + b0.y, 0.f);
            f0.z = fmaxf(f0.z * a0.z + b0.z, 0.f); f0.w = fmaxf(f0.w * a0.w + b0.w, 0.f);
            f1.x = fmaxf(f1.x * a1.x + b1.x, 0.f); f1.y = fmaxf(f1.y * a1.y + b1.y, 0.f);
            f1.z = fmaxf(f1.z * a1.z + b1.z, 0.f); f1.w = fmaxf(f1.w * a1.w + b1.w, 0.f);
            f2.x = fmaxf(f2.x * a2.x + b2.x, 0.f); f2.y = fmaxf(f2.y * a2.y + b2.y, 0.f);
            f2.z = fmaxf(f2.z * a2.z + b2.z, 0.f); f2.w = fmaxf(f2.w * a2.w + b2.w, 0.f);
            f3.x = fmaxf(f3.x * a3.x + b3.x, 0.f); f3.y = fmaxf(f3.y * a3.y + b3.y, 0.f);
            f3.z = fmaxf(f3.z * a3.z + b3.z, 0.f); f3.w = fmaxf(f3.w * a3.w + b3.w, 0.f);
        }
        uint4 p0, p1;
        p0.x = (unsigned)f2bf(f0.x) | ((unsigned)f2bf(f0.y) << 16);
        p0.y = (unsigned)f2bf(f0.z) | ((unsigned)f2bf(f0.w) << 16);
        p0.z = (unsigned)f2bf(f1.x) | ((unsigned)f2bf(f1.y) << 16);
        p0.w = (unsigned)f2bf(f1.z) | ((unsigned)f2bf(f1.w) << 16);
        p1.x = (unsigned)f2bf(f2.x) | ((unsigned)f2bf(f2.y) << 16);
        p1.y = (unsigned)f2bf(f2.z) | ((unsigned)f2bf(f2.w) << 16);
        p1.z = (unsigned)f2bf(f3.x) | ((unsigned)f2bf(f3.y) << 16);
        p1.w = (unsigned)f2bf(f3.z) | ((unsigned)f2bf(f3.w) << 16);
        unsigned sw = (unsigned)((r & 7) << 4);
        *reinterpret_cast<uint4*>(&ldsA[r * 256 + (((unsigned)(seg * 32)) ^ sw)]) = p0;
        *reinterpret_cast<uint4*>(&ldsA[r * 256 + (((unsigned)(seg * 32 + 16)) ^ sw)]) = p1;
    }
    __syncthreads();

    int lane = t & 63, w = t >> 6;
    int m = w >> 1, half = w & 1;
    int lrow = lane & 15, lk = lane >> 4;

    f32x4 acc[4][4] = {};
    #pragma unroll
    for (int ks = 0; ks < 4; ks++) {
        bf16x8 bfr[4], af[4];
        #pragma unroll
        for (int j = 0; j < 4; j++) {
            int col = half * 64 + j * 16 + lrow;
            bfr[j] = *reinterpret_cast<const bf16x8*>(
                &WT[((size_t)m * 128 + col) * 128 + ks * 32 + lk * 8]);
        }
        #pragma unroll
        for (int i = 0; i < 4; i++) {
            unsigned row = (unsigned)(i * 16 + lrow);
            af[i] = *reinterpret_cast<const bf16x8*>(
                &ldsA[row * 256 + (((unsigned)(ks * 64 + lk * 16)) ^ ((row & 7) << 4))]);
        }
        #pragma unroll
        for (int i = 0; i < 4; i++)
            #pragma unroll
            for (int j = 0; j < 4; j++)
                acc[i][j] = __builtin_amdgcn_mfma_f32_16x16x32_bf16(af[i], bfr[j], acc[i][j], 0, 0, 0);
    }

    // ---- epilogue ----
    const float* bias = (m == 0) ? bq : (m == 1) ? bk : (m == 2) ? bv : bs;
    if (m == 0 || m == 3) {
        float* ob = (m == 0) ? qb : hb;
        #pragma unroll
        for (int j = 0; j < 4; j++) {
            int c = half * 64 + j * 16 + lrow;
            float bi = bias[c];
            #pragma unroll
            for (int i = 0; i < 4; i++)
                #pragma unroll
                for (int r4 = 0; r4 < 4; r4++) {
                    int row = n0 + i * 16 + lk * 4 + r4;
                    ob[(size_t)row * 128 + c] = acc[i][j][r4] + bi;
                }
        }
    } else {
        unsigned vOff = (m == 1) ? 0u : 256u;
        #pragma unroll
        for (int j = 0; j < 4; j++) {
            int c = half * 64 + j * 16 + lrow;
            float bi = bias[c];
            unsigned bir = vOff + (unsigned)c * 2;
            #pragma unroll
            for (int i = 0; i < 4; i++)
                #pragma unroll
                for (int r4 = 0; r4 < 4; r4++) {
                    unsigned row = (unsigned)(i * 16 + lk * 4 + r4);
                    unsigned sw = ((row >> 2) & 3) << 5;
                    *reinterpret_cast<unsigned short*>(&ldsKV[row * 512 + (bir ^ sw)]) =
                        f2bf(acc[i][j][r4] + bi);
                }
        }
    }
    __syncthreads();
    // coalesced kv write-out: 8 threads/row, 64B each -> full 512B rows
    {
        int r = t >> 3, seg = t & 7;
        unsigned sw = (((unsigned)r >> 2) & 3) << 5;
        char* dst = (char*)(kvb + (size_t)(n0 + r) * 256) + seg * 64;
        #pragma unroll
        for (int u = 0; u < 4; u++) {
            uint4 v = *reinterpret_cast<const uint4*>(
                &ldsKV[r * 512 + (((unsigned)(seg * 64 + u * 16)) ^ sw)]);
            *reinterpret_cast<uint4*>(dst + u * 16) = v;
        }
    }
}

// ---------------- Attention aggregation: 16 lanes/edge, 4 edges in flight ----
__global__ __launch_bounds__(256) void agg_kernel(
    const float* __restrict__ qb, const unsigned short* __restrict__ kvb,
    const int* __restrict__ row_ptr, const int* __restrict__ edge_src,
    float* __restrict__ hb)
{
    int wave = threadIdx.x >> 6, lane = threadIdx.x & 63;
    int n = blockIdx.x * 4 + wave;
    int quarter = lane >> 4, ql = lane & 15;

    float4 qa = *reinterpret_cast<const float4*>(&qb[(size_t)n * 128 + ql * 8]);
    float4 qc = *reinterpret_cast<const float4*>(&qb[(size_t)n * 128 + ql * 8 + 4]);
    int s0 = row_ptr[n], s1 = row_ptr[n + 1];

    float acc0 = 0.f, acc1 = 0.f, acc2 = 0.f, acc3 = 0.f;
    float acc4 = 0.f, acc5 = 0.f, acc6 = 0.f, acc7 = 0.f;
    float ssum = 0.f;

    for (int j0 = s0; j0 < s1; j0 += 4) {
        int j = j0 + quarter;
        bool act = (j < s1);
        int s = act ? edge_src[j] : 0;
        const uint4* kv4 = reinterpret_cast<const uint4*>(kvb + (size_t)s * 256);
        uint4 kr = kv4[ql];
        uint4 vr = kv4[16 + ql];

        float part = qa.x * bflo(kr.x) + qa.y * bfhi(kr.x)
                   + qa.z * bflo(kr.y) + qa.w * bfhi(kr.y)
                   + qc.x * bflo(kr.z) + qc.y * bfhi(kr.z)
                   + qc.z * bflo(kr.w) + qc.w * bfhi(kr.w);
        part += __shfl_xor(part, 1, 64);
        part += __shfl_xor(part, 2, 64);
        part += __shfl_xor(part, 4, 64);
        part += __shfl_xor(part, 8, 64);

        float wgt = act ? __expf(part * ATT_SCALE) : 0.f;
        ssum += wgt;
        acc0 += wgt * bflo(vr.x); acc1 += wgt * bfhi(vr.x);
        acc2 += wgt * bflo(vr.y); acc3 += wgt * bfhi(vr.y);
        acc4 += wgt * bflo(vr.z); acc5 += wgt * bfhi(vr.z);
        acc6 += wgt * bflo(vr.w); acc7 += wgt * bfhi(vr.w);
    }

    #define XRED(x) { x += __shfl_xor(x, 16, 64); x += __shfl_xor(x, 32, 64); }
    XRED(acc0) XRED(acc1) XRED(acc2) XRED(acc3)
    XRED(acc4) XRED(acc5) XRED(acc6) XRED(acc7)
    XRED(ssum)
    #undef XRED

    if (quarter == 0) {
        float inv = 1.0f / (ssum + 1e-16f);
        float4 h0 = *reinterpret_cast<float4*>(&hb[(size_t)n * 128 + ql * 8]);
        float4 h1 = *reinterpret_cast<float4*>(&hb[(size_t)n * 128 + ql * 8 + 4]);
        h0.x += acc0 * inv; h0.y += acc1 * inv; h0.z += acc2 * inv; h0.w += acc3 * inv;
        h1.x += acc4 * inv; h1.y += acc5 * inv; h1.z += acc6 * inv; h1.w += acc7 * inv;
        *reinterpret_cast<float4*>(&hb[(size_t)n * 128 + ql * 8]) = h0;
        *reinterpret_cast<float4*>(&hb[(size_t)n * 128 + ql * 8 + 4]) = h1;
    }
}

// ---------------- BatchNorm statistics ----------------
__global__ __launch_bounds__(256) void bn_stats(const float* __restrict__ h,
                                                float* __restrict__ sums,
                                                float* __restrict__ sqs) {
    int t = threadIdx.x;
    int c = t & 127;
    float s = 0.f, q = 0.f;
    int stride = gridDim.x * 256;
    for (int i = blockIdx.x * 256 + t; i < N_NODES * 128; i += stride) {
        float v = h[i];
        s += v; q += v * v;
    }
    __shared__ float sh[256], shq[256];
    sh[t] = s; shq[t] = q;
    __syncthreads();
    if (t < 128) {
        atomicAdd(&sums[c], sh[t] + sh[t + 128]);
        atomicAdd(&sqs[c],  shq[t] + shq[t + 128]);
    }
}

__global__ void bn_final(const float* __restrict__ sums, const float* __restrict__ sqs,
                         const float* __restrict__ g, const float* __restrict__ be,
                         float* __restrict__ a, float* __restrict__ b) {
    int c = threadIdx.x;
    float mean = sums[c] / (float)N_NODES;
    float var  = sqs[c] / (float)N_NODES - mean * mean;
    float inv  = rsqrtf(var + BN_EPS);
    float av   = g[c] * inv;
    a[c] = av;
    b[c] = be[c] - mean * av;
}

// ---------------- Final FC head: 8 nodes per 256-thread block ----------------
__global__ __launch_bounds__(256) void fc_kernel(
    const float* __restrict__ h2, const float* __restrict__ a1, const float* __restrict__ b1,
    const int* __restrict__ ptr, const float* __restrict__ gf,
    const float* __restrict__ fcW, const float* __restrict__ fcb,
    const float* __restrict__ fc2W, const float* __restrict__ fc2b,
    float* __restrict__ out)
{
    __shared__ float hc[8][144];
    __shared__ float red[8][128];
    int t = threadIdx.x;
    int nb = blockIdx.x * 8;

    {
        int node_l = t >> 5, li = t & 31;
        int n = nb + node_l;
        float4 v = *reinterpret_cast<const float4*>(&h2[(size_t)n * 128 + li * 4]);
        float4 av = *reinterpret_cast<const float4*>(&a1[li * 4]);
        float4 bv = *reinterpret_cast<const float4*>(&b1[li * 4]);
        hc[node_l][li * 4 + 0] = fmaxf(v.x * av.x + bv.x, 0.f);
        hc[node_l][li * 4 + 1] = fmaxf(v.y * av.y + bv.y, 0.f);
        hc[node_l][li * 4 + 2] = fmaxf(v.z * av.z + bv.z, 0.f);
        hc[node_l][li * 4 + 3] = fmaxf(v.w * av.w + bv.w, 0.f);
        if (li < 16) {
            int lo = 0, hi = NGRAPH;
            while (lo < hi) {
                int mid = (lo + hi + 1) >> 1;
                if (ptr[mid] <= n) lo = mid; else hi = mid - 1;
            }
            hc[node_l][128 + li] = gf[lo * 16 + li];
        }
    }
    __syncthreads();

    {
        int half = t >> 7, o = t & 127;
        float fb = fcb[o];
        float acc0 = fb, acc1 = fb, acc2 = fb, acc3 = fb;
        const float* h0 = hc[half * 4 + 0];
        const float* h1 = hc[half * 4 + 1];
        const float* h2c = hc[half * 4 + 2];
        const float* h3 = hc[half * 4 + 3];
        #pragma unroll 16
        for (int i = 0; i < 144; i++) {
            float w = fcW[i * 128 + o];
            acc0 += h0[i] * w;
            acc1 += h1[i] * w;
            acc2 += h2c[i] * w;
            acc3 += h3[i] * w;
        }
        float w2 = fc2W[o];
        red[half * 4 + 0][o] = fmaxf(acc0, 0.f) * w2;
        red[half * 4 + 1][o] = fmaxf(acc1, 0.f) * w2;
        red[half * 4 + 2][o] = fmaxf(acc2, 0.f) * w2;
        red[half * 4 + 3][o] = fmaxf(acc3, 0.f) * w2;
    }
    __syncthreads();

    {
        int node_l = t >> 5, li = t & 31;
        float s = red[node_l][li] + red[node_l][li + 32]
                + red[node_l][li + 64] + red[node_l][li + 96];
        s += __shfl_xor(s, 1, 64);
        s += __shfl_xor(s, 2, 64);
        s += __shfl_xor(s, 4, 64);
        s += __shfl_xor(s, 8, 64);
        s += __shfl_xor(s, 16, 64);
        if (li == 0) out[nb + node_l] = s + fc2b[0];
    }
}

// ---------------- launch ----------------
extern "C" void kernel_launch(void* const* d_in, const int* in_sizes, int n_in,
                              void* d_out, int out_size, void* d_ws, size_t ws_size,
                              hipStream_t stream)
{
    const float* x   = (const float*)d_in[0];
    const int*   ei  = (const int*)d_in[1];
    const int*   ptr = (const int*)d_in[2];
    const float* gf  = (const float*)d_in[3];
    const float* Wq0 = (const float*)d_in[4];
    const float* Wk0 = (const float*)d_in[5];
    const float* Wv0 = (const float*)d_in[6];
    const float* Ws0 = (const float*)d_in[7];
    const float* bq0 = (const float*)d_in[8];
    const float* bk0 = (const float*)d_in[9];
    const float* bv0 = (const float*)d_in[10];
    const float* bs0 = (const float*)d_in[11];
    const float* g0  = (const float*)d_in[12];
    const float* be0 = (const float*)d_in[13];
    const float* Wq1 = (const float*)d_in[14];
    const float* Wk1 = (const float*)d_in[15];
    const float* Wv1 = (const float*)d_in[16];
    const float* Ws1 = (const float*)d_in[17];
    const float* bq1 = (const float*)d_in[18];
    const float* bk1 = (const float*)d_in[19];
    const float* bv1 = (const float*)d_in[20];
    const float* bs1 = (const float*)d_in[21];
    const float* g1  = (const float*)d_in[22];
    const float* be1 = (const float*)d_in[23];
    const float* fcW = (const float*)d_in[24];
    const float* fcb = (const float*)d_in[25];
    const float* fc2W= (const float*)d_in[26];
    const float* fc2b= (const float*)d_in[27];
    float* out = (float*)d_out;

    const int* src_p = ei;
    const int* dst_p = ei + N_EDGES;

    char* w = (char*)d_ws;
    const size_t NM = (size_t)N_NODES * 128 * sizeof(float);
    float* qb = (float*)w;                    w += NM;
    unsigned short* kvb = (unsigned short*)w; w += (size_t)N_NODES * 256 * sizeof(unsigned short);
    float* h1 = (float*)w;                    w += NM;
    float* h2 = (float*)w;                    w += NM;
    float* stats = (float*)w;                 w += 1024 * sizeof(float);
    float* sums0 = stats;
    float* sqs0  = stats + 128;
    float* sums1 = stats + 256;
    float* sqs1  = stats + 384;
    float* a0    = stats + 512;
    float* b0    = stats + 640;
    float* a1    = stats + 768;
    float* b1    = stats + 896;
    unsigned short* WT0 = (unsigned short*)w; w += (size_t)512 * 128 * sizeof(unsigned short);
    unsigned short* WT1 = (unsigned short*)w; w += (size_t)512 * 128 * sizeof(unsigned short);
    int* cnt     = (int*)w;                   w += (size_t)N_NODES * sizeof(int);
    int* row_ptr = (int*)w;                   w += (size_t)(N_NODES + 1) * sizeof(int);
    int* cur     = (int*)w;                   w += (size_t)N_NODES * sizeof(int);
    int* edge_src= (int*)w;                   w += (size_t)N_EDGES * sizeof(int);
    int* bsum    = (int*)w;                   w += 64 * sizeof(int);
    int* boff    = (int*)w;                   w += 64 * sizeof(int);

    hipMemsetAsync(cnt, 0, (size_t)N_NODES * sizeof(int), stream);
    hipMemsetAsync(stats, 0, 512 * sizeof(float), stream);

    // Weight prep (both layers)
    wprep_kernel<<<4, 256, 0, stream>>>(Wq0, Wk0, Wv0, Ws0, WT0);
    wprep_kernel<<<4, 256, 0, stream>>>(Wq1, Wk1, Wv1, Ws1, WT1);

    // CSR build (reused by both layers)
    hist_kernel<<<3136, 256, 0, stream>>>(dst_p, cnt);
    scan1_kernel<<<49, 256, 0, stream>>>(cnt, row_ptr, bsum);
    scan2_kernel<<<1, 1, 0, stream>>>(bsum, boff, row_ptr);
    scan3_kernel<<<49, 256, 0, stream>>>(row_ptr, cur, boff);
    scatter_kernel<<<3136, 256, 0, stream>>>(src_p, dst_p, cur, edge_src);

    // Layer 0
    gemm_mfma<<<784, 512, 0, stream>>>(x, WT0,
        bq0, bk0, bv0, bs0, qb, kvb, h1, nullptr, nullptr);
    agg_kernel<<<12544, 256, 0, stream>>>(qb, kvb, row_ptr, edge_src, h1);
    bn_stats<<<784, 256, 0, stream>>>(h1, sums0, sqs0);
    bn_final<<<1, 128, 0, stream>>>(sums0, sqs0, g0, be0, a0, b0);

    // Layer 1 (BN+ReLU fused into GEMM A-staging)
    gemm_mfma<<<784, 512, 0, stream>>>(h1, WT1,
        bq1, bk1, bv1, bs1, qb, kvb, h2, a0, b0);
    agg_kernel<<<12544, 256, 0, stream>>>(qb, kvb, row_ptr, edge_src, h2);
    bn_stats<<<784, 256, 0, stream>>>(h2, sums1, sqs1);
    bn_final<<<1, 128, 0, stream>>>(sums1, sqs1, g1, be1, a1, b1);

    // Head
    fc_kernel<<<6272, 256, 0, stream>>>(h2, a1, b1, ptr, gf,
        fcW, fcb, fc2W, fc2b, out);
}

// Round 6
// 509.498 us; speedup vs baseline: 1.6924x; 1.0195x over previous
//
#include <hip/hip_runtime.h>
#include <math.h>

#define N_NODES 50176
#define N_EDGES 802816
#define HIDDEN  128
#define NGRAPH  64
#define BN_EPS  1e-5f
#define ATT_SCALE 0.08838834764831845f  // 1/sqrt(128)

typedef __attribute__((ext_vector_type(8))) short bf16x8;
typedef __attribute__((ext_vector_type(4))) float f32x4;

__device__ __forceinline__ float bflo(unsigned u) { return __uint_as_float(u << 16); }
__device__ __forceinline__ float bfhi(unsigned u) { return __uint_as_float(u & 0xffff0000u); }
__device__ __forceinline__ unsigned short f2bf(float f) {
    unsigned u = __float_as_uint(f);
    unsigned r = (u + 0x7fffu + ((u >> 16) & 1u)) >> 16;
    return (unsigned short)r;
}

// BN affine from raw sums: a = g*rsqrt(var+eps), b = be - mean*a  (4 channels)
__device__ __forceinline__ void bn_ab4(const float* __restrict__ S, const float* __restrict__ Q,
                                       const float* __restrict__ G, const float* __restrict__ BE,
                                       int c, float4& A, float4& B) {
    const float invN = 1.0f / (float)N_NODES;
    float4 s = *reinterpret_cast<const float4*>(&S[c]);
    float4 q = *reinterpret_cast<const float4*>(&Q[c]);
    float4 g = *reinterpret_cast<const float4*>(&G[c]);
    float4 e = *reinterpret_cast<const float4*>(&BE[c]);
    #define BNC(x) { float mu = s.x * invN; float va = q.x * invN - mu * mu; \
                     float iv = rsqrtf(va + BN_EPS); A.x = g.x * iv; B.x = e.x - mu * A.x; }
    BNC(x) BNC(y) BNC(z) BNC(w)
    #undef BNC
}

// ---------------- CSR build ----------------
__global__ void hist_kernel(const int* __restrict__ dst, int* __restrict__ cnt) {
    int e = blockIdx.x * 256 + threadIdx.x;
    if (e < N_EDGES) atomicAdd(&cnt[dst[e]], 1);
}

__global__ void scan1_kernel(const int* __restrict__ cnt, int* __restrict__ row_ptr,
                             int* __restrict__ bsum) {
    __shared__ int sh[256];
    int t = threadIdx.x, b = blockIdx.x;
    int base = b * 1024 + t * 4;
    int v0 = cnt[base], v1 = cnt[base + 1], v2 = cnt[base + 2], v3 = cnt[base + 3];
    int tot = v0 + v1 + v2 + v3;
    sh[t] = tot; __syncthreads();
    for (int off = 1; off < 256; off <<= 1) {
        int x = (t >= off) ? sh[t - off] : 0;
        __syncthreads();
        sh[t] += x;
        __syncthreads();
    }
    int excl = sh[t] - tot;
    row_ptr[base]     = excl;
    row_ptr[base + 1] = excl + v0;
    row_ptr[base + 2] = excl + v0 + v1;
    row_ptr[base + 3] = excl + v0 + v1 + v2;
    if (t == 255) bsum[b] = sh[255];
}

// scan2 folded in: each block redundantly scans the 49 block sums with shuffles.
__global__ void scan3_kernel(int* __restrict__ row_ptr, int* __restrict__ cur,
                             const int* __restrict__ bsum) {
    __shared__ int sh_off;
    int t = threadIdx.x, b = blockIdx.x;
    if (t < 64) {
        int v = (t < 49) ? bsum[t] : 0;
        int inc = v;
        #pragma unroll
        for (int o = 1; o < 64; o <<= 1) {
            int u = __shfl_up(inc, o, 64);
            if (t >= o) inc += u;
        }
        if (t == b) sh_off = inc - v;            // exclusive prefix for this block
        if (b == 48 && t == 48) row_ptr[N_NODES] = inc;
    }
    __syncthreads();
    int off = sh_off;
    int base = b * 1024 + t * 4;
    #pragma unroll
    for (int j = 0; j < 4; j++) {
        int v = row_ptr[base + j] + off;
        row_ptr[base + j] = v;
        cur[base + j] = v;
    }
}

__global__ void scatter_kernel(const int* __restrict__ src, const int* __restrict__ dst,
                               int* __restrict__ cur, int* __restrict__ edge_src) {
    int e = blockIdx.x * 256 + threadIdx.x;
    if (e < N_EDGES) {
        int d = dst[e];
        int slot = atomicAdd(&cur[d], 1);
        edge_src[slot] = src[e];
    }
}

// ---------------- Weight prep: f32 [128k][128c] -> bf16 WT [mat][c][k] ------
__global__ void wprep_kernel(const float* __restrict__ Wq, const float* __restrict__ Wk,
                             const float* __restrict__ Wv, const float* __restrict__ Ws,
                             unsigned short* __restrict__ WT) {
    int mb = blockIdx.x;
    const float* W = (mb == 0) ? Wq : (mb == 1) ? Wk : (mb == 2) ? Wv : Ws;
    int t = threadIdx.x;
    int k = t >> 1, ch = t & 1;
    #pragma unroll 8
    for (int cc = 0; cc < 64; cc++) {
        int c = ch * 64 + cc;
        WT[((size_t)mb * 128 + c) * 128 + k] = f2bf(W[k * 128 + c]);
    }
}

// ---------------- MFMA projection GEMM (single pass over A) -----------------
// Grid 784, block 512 (8 waves). Block tile = 64 rows x 512 cols.
// Wave w: matrix m = w>>1, col half = w&1. A staged ONCE in LDS (bf16,
// swizzled); B from pre-transposed WT (L2-resident). q (bf16) re-uses ldsA
// post-barrier, k/v go through ldsKV -> fully coalesced row writes.
// BN affine computed inline from raw sums (layer 1).
__global__ __launch_bounds__(512, 4) void gemm_mfma(
    const float* __restrict__ in,
    const unsigned short* __restrict__ WT,
    const float* __restrict__ bq, const float* __restrict__ bk,
    const float* __restrict__ bv, const float* __restrict__ bs,
    unsigned short* __restrict__ qbf, unsigned short* __restrict__ kvb,
    float* __restrict__ hb,
    const float* __restrict__ bnS, const float* __restrict__ bnQ,
    const float* __restrict__ bnG, const float* __restrict__ bnBe)
{
    __shared__ unsigned char ldsA[16384];    // 64 rows x 256B (128 bf16), swizzled
    __shared__ unsigned char ldsKV[32768];   // 64 rows x 512B (k|v ushorts), swizzled
    int t = threadIdx.x;
    int n0 = blockIdx.x * 64;

    // ---- stage A once: fp32 (+opt BN/ReLU from raw sums) -> bf16 LDS ----
    {
        int r = t >> 3, seg = t & 7;         // 8 threads/row, 16 floats each
        const float* srcp = in + (size_t)(n0 + r) * 128 + seg * 16;
        float4 f0 = *reinterpret_cast<const float4*>(srcp);
        float4 f1 = *reinterpret_cast<const float4*>(srcp + 4);
        float4 f2 = *reinterpret_cast<const float4*>(srcp + 8);
        float4 f3 = *reinterpret_cast<const float4*>(srcp + 12);
        if (bnS) {
            int kb = seg * 16;
            float4 a0, b0, a1, b1, a2, b2, a3, b3;
            bn_ab4(bnS, bnQ, bnG, bnBe, kb,      a0, b0);
            bn_ab4(bnS, bnQ, bnG, bnBe, kb + 4,  a1, b1);
            bn_ab4(bnS, bnQ, bnG, bnBe, kb + 8,  a2, b2);
            bn_ab4(bnS, bnQ, bnG, bnBe, kb + 12, a3, b3);
            f0.x = fmaxf(f0.x * a0.x + b0.x, 0.f); f0.y = fmaxf(f0.y * a0.y + b0.y, 0.f);
            f0.z = fmaxf(f0.z * a0.z + b0.z, 0.f); f0.w = fmaxf(f0.w * a0.w + b0.w, 0.f);
            f1.x = fmaxf(f1.x * a1.x + b1.x, 0.f); f1.y = fmaxf(f1.y * a1.y + b1.y, 0.f);
            f1.z = fmaxf(f1.z * a1.z + b1.z, 0.f); f1.w = fmaxf(f1.w * a1.w + b1.w, 0.f);
            f2.x = fmaxf(f2.x * a2.x + b2.x, 0.f); f2.y = fmaxf(f2.y * a2.y + b2.y, 0.f);
            f2.z = fmaxf(f2.z * a2.z + b2.z, 0.f); f2.w = fmaxf(f2.w * a2.w + b2.w, 0.f);
            f3.x = fmaxf(f3.x * a3.x + b3.x, 0.f); f3.y = fmaxf(f3.y * a3.y + b3.y, 0.f);
            f3.z = fmaxf(f3.z * a3.z + b3.z, 0.f); f3.w = fmaxf(f3.w * a3.w + b3.w, 0.f);
        }
        uint4 p0, p1;
        p0.x = (unsigned)f2bf(f0.x) | ((unsigned)f2bf(f0.y) << 16);
        p0.y = (unsigned)f2bf(f0.z) | ((unsigned)f2bf(f0.w) << 16);
        p0.z = (unsigned)f2bf(f1.x) | ((unsigned)f2bf(f1.y) << 16);
        p0.w = (unsigned)f2bf(f1.z) | ((unsigned)f2bf(f1.w) << 16);
        p1.x = (unsigned)f2bf(f2.x) | ((unsigned)f2bf(f2.y) << 16);
        p1.y = (unsigned)f2bf(f2.z) | ((unsigned)f2bf(f2.w) << 16);
        p1.z = (unsigned)f2bf(f3.x) | ((unsigned)f2bf(f3.y) << 16);
        p1.w = (unsigned)f2bf(f3.z) | ((unsigned)f2bf(f3.w) << 16);
        unsigned sw = (unsigned)((r & 7) << 4);
        *reinterpret_cast<uint4*>(&ldsA[r * 256 + (((unsigned)(seg * 32)) ^ sw)]) = p0;
        *reinterpret_cast<uint4*>(&ldsA[r * 256 + (((unsigned)(seg * 32 + 16)) ^ sw)]) = p1;
    }
    __syncthreads();

    int lane = t & 63, w = t >> 6;
    int m = w >> 1, half = w & 1;
    int lrow = lane & 15, lk = lane >> 4;

    f32x4 acc[4][4] = {};
    #pragma unroll
    for (int ks = 0; ks < 4; ks++) {
        bf16x8 bfr[4], af[4];
        #pragma unroll
        for (int j = 0; j < 4; j++) {
            int col = half * 64 + j * 16 + lrow;
            bfr[j] = *reinterpret_cast<const bf16x8*>(
                &WT[((size_t)m * 128 + col) * 128 + ks * 32 + lk * 8]);
        }
        #pragma unroll
        for (int i = 0; i < 4; i++) {
            unsigned row = (unsigned)(i * 16 + lrow);
            af[i] = *reinterpret_cast<const bf16x8*>(
                &ldsA[row * 256 + (((unsigned)(ks * 64 + lk * 16)) ^ ((row & 7) << 4))]);
        }
        #pragma unroll
        for (int i = 0; i < 4; i++)
            #pragma unroll
            for (int j = 0; j < 4; j++)
                acc[i][j] = __builtin_amdgcn_mfma_f32_16x16x32_bf16(af[i], bfr[j], acc[i][j], 0, 0, 0);
    }

    __syncthreads();   // everyone done reading ldsA; safe to re-use for q

    // ---- epilogue ----
    const float* bias = (m == 0) ? bq : (m == 1) ? bk : (m == 2) ? bv : bs;
    if (m == 3) {
        #pragma unroll
        for (int j = 0; j < 4; j++) {
            int c = half * 64 + j * 16 + lrow;
            float bi = bias[c];
            #pragma unroll
            for (int i = 0; i < 4; i++)
                #pragma unroll
                for (int r4 = 0; r4 < 4; r4++) {
                    int row = n0 + i * 16 + lk * 4 + r4;
                    hb[(size_t)row * 128 + c] = acc[i][j][r4] + bi;
                }
        }
    } else if (m == 0) {
        // q -> bf16 into ldsA (swizzled)
        #pragma unroll
        for (int j = 0; j < 4; j++) {
            int c = half * 64 + j * 16 + lrow;
            float bi = bias[c];
            #pragma unroll
            for (int i = 0; i < 4; i++)
                #pragma unroll
                for (int r4 = 0; r4 < 4; r4++) {
                    unsigned row = (unsigned)(i * 16 + lk * 4 + r4);
                    unsigned sw = ((row >> 2) & 3) << 5;
                    *reinterpret_cast<unsigned short*>(
                        &ldsA[row * 256 + (((unsigned)(2 * c)) ^ sw)]) =
                        f2bf(acc[i][j][r4] + bi);
                }
        }
    } else {
        unsigned vOff = (m == 1) ? 0u : 256u;
        #pragma unroll
        for (int j = 0; j < 4; j++) {
            int c = half * 64 + j * 16 + lrow;
            float bi = bias[c];
            unsigned bir = vOff + (unsigned)c * 2;
            #pragma unroll
            for (int i = 0; i < 4; i++)
                #pragma unroll
                for (int r4 = 0; r4 < 4; r4++) {
                    unsigned row = (unsigned)(i * 16 + lk * 4 + r4);
                    unsigned sw = ((row >> 2) & 3) << 5;
                    *reinterpret_cast<unsigned short*>(&ldsKV[row * 512 + (bir ^ sw)]) =
                        f2bf(acc[i][j][r4] + bi);
                }
        }
    }
    __syncthreads();

    // coalesced write-out: q rows (256B) + kv rows (512B)
    {
        int r = t >> 3, seg = t & 7;
        unsigned sw = (((unsigned)r >> 2) & 3) << 5;
        // q: 8 threads/row, 32B each
        char* qdst = (char*)(qbf + (size_t)(n0 + r) * 128) + seg * 32;
        uint4 v0 = *reinterpret_cast<const uint4*>(
            &ldsA[r * 256 + (((unsigned)(seg * 32)) ^ sw)]);
        uint4 v1 = *reinterpret_cast<const uint4*>(
            &ldsA[r * 256 + ((((unsigned)(seg * 32)) ^ sw) + 16)]);
        *reinterpret_cast<uint4*>(qdst) = v0;
        *reinterpret_cast<uint4*>(qdst + 16) = v1;
        // kv: 8 threads/row, 64B each
        char* dst = (char*)(kvb + (size_t)(n0 + r) * 256) + seg * 64;
        #pragma unroll
        for (int u = 0; u < 4; u++) {
            uint4 v = *reinterpret_cast<const uint4*>(
                &ldsKV[r * 512 + (((unsigned)(seg * 64 + u * 16)) ^ sw)]);
            *reinterpret_cast<uint4*>(dst + u * 16) = v;
        }
    }
}

// ---------------- Attention aggregation ----
// 16 lanes/edge, 4 edges/wave-iter, unrolled x2 => 8 edges in flight.
__global__ __launch_bounds__(256) void agg_kernel(
    const unsigned short* __restrict__ qbf, const unsigned short* __restrict__ kvb,
    const int* __restrict__ row_ptr, const int* __restrict__ edge_src,
    float* __restrict__ hb)
{
    int wave = threadIdx.x >> 6, lane = threadIdx.x & 63;
    int n = blockIdx.x * 4 + wave;
    int quarter = lane >> 4, ql = lane & 15;

    uint4 qr = reinterpret_cast<const uint4*>(qbf + (size_t)n * 128)[ql];
    float q0 = bflo(qr.x), q1 = bfhi(qr.x), q2 = bflo(qr.y), q3 = bfhi(qr.y);
    float q4v = bflo(qr.z), q5 = bfhi(qr.z), q6 = bflo(qr.w), q7 = bfhi(qr.w);

    int s0 = row_ptr[n], s1 = row_ptr[n + 1];

    float acc0 = 0.f, acc1 = 0.f, acc2 = 0.f, acc3 = 0.f;
    float acc4 = 0.f, acc5 = 0.f, acc6 = 0.f, acc7 = 0.f;
    float ssum = 0.f;

    #define EDGE_ACC(kr, vr, act)                                          \
    {                                                                      \
        float part = q0 * bflo(kr.x) + q1 * bfhi(kr.x)                     \
                   + q2 * bflo(kr.y) + q3 * bfhi(kr.y)                     \
                   + q4v * bflo(kr.z) + q5 * bfhi(kr.z)                    \
                   + q6 * bflo(kr.w) + q7 * bfhi(kr.w);                    \
        part += __shfl_xor(part, 1, 64);                                   \
        part += __shfl_xor(part, 2, 64);                                   \
        part += __shfl_xor(part, 4, 64);                                   \
        part += __shfl_xor(part, 8, 64);                                   \
        float wgt = (act) ? __expf(part * ATT_SCALE) : 0.f;                \
        ssum += wgt;                                                       \
        acc0 += wgt * bflo(vr.x); acc1 += wgt * bfhi(vr.x);                \
        acc2 += wgt * bflo(vr.y); acc3 += wgt * bfhi(vr.y);                \
        acc4 += wgt * bflo(vr.z); acc5 += wgt * bfhi(vr.z);                \
        acc6 += wgt * bflo(vr.w); acc7 += wgt * bfhi(vr.w);                \
    }

    for (int j0 = s0; j0 < s1; j0 += 8) {
        int ja = j0 + quarter;
        int jb = ja + 4;
        bool aa = ja < s1, ab = jb < s1;
        int sa = aa ? edge_src[ja] : 0;
        int sb = ab ? edge_src[jb] : 0;
        const uint4* pa = reinterpret_cast<const uint4*>(kvb + (size_t)sa * 256);
        const uint4* pb = reinterpret_cast<const uint4*>(kvb + (size_t)sb * 256);
        uint4 kra = pa[ql], vra = pa[16 + ql];
        uint4 krb = pb[ql], vrb = pb[16 + ql];
        EDGE_ACC(kra, vra, aa)
        EDGE_ACC(krb, vrb, ab)
    }
    #undef EDGE_ACC

    #define XRED(x) { x += __shfl_xor(x, 16, 64); x += __shfl_xor(x, 32, 64); }
    XRED(acc0) XRED(acc1) XRED(acc2) XRED(acc3)
    XRED(acc4) XRED(acc5) XRED(acc6) XRED(acc7)
    XRED(ssum)
    #undef XRED

    if (quarter == 0) {
        float inv = 1.0f / (ssum + 1e-16f);
        float4 h0 = *reinterpret_cast<float4*>(&hb[(size_t)n * 128 + ql * 8]);
        float4 h1 = *reinterpret_cast<float4*>(&hb[(size_t)n * 128 + ql * 8 + 4]);
        h0.x += acc0 * inv; h0.y += acc1 * inv; h0.z += acc2 * inv; h0.w += acc3 * inv;
        h1.x += acc4 * inv; h1.y += acc5 * inv; h1.z += acc6 * inv; h1.w += acc7 * inv;
        *reinterpret_cast<float4*>(&hb[(size_t)n * 128 + ql * 8]) = h0;
        *reinterpret_cast<float4*>(&hb[(size_t)n * 128 + ql * 8 + 4]) = h1;
    }
}

// ---------------- BatchNorm statistics (float4) ----------------
__global__ __launch_bounds__(256) void bn_stats(const float* __restrict__ h,
                                                float* __restrict__ sums,
                                                float* __restrict__ sqs) {
    int t = threadIdx.x;
    float4 s4 = make_float4(0.f, 0.f, 0.f, 0.f);
    float4 q4 = make_float4(0.f, 0.f, 0.f, 0.f);
    const int stride = 784 * 256;
    for (int i = blockIdx.x * 256 + t; i < N_NODES * 32; i += stride) {
        float4 v = reinterpret_cast<const float4*>(h)[i];
        s4.x += v.x; s4.y += v.y; s4.z += v.z; s4.w += v.w;
        q4.x += v.x * v.x; q4.y += v.y * v.y; q4.z += v.z * v.z; q4.w += v.w * v.w;
    }
    __shared__ float sh_s[1024], sh_q[1024];
    sh_s[t * 4 + 0] = s4.x; sh_s[t * 4 + 1] = s4.y; sh_s[t * 4 + 2] = s4.z; sh_s[t * 4 + 3] = s4.w;
    sh_q[t * 4 + 0] = q4.x; sh_q[t * 4 + 1] = q4.y; sh_q[t * 4 + 2] = q4.z; sh_q[t * 4 + 3] = q4.w;
    __syncthreads();
    if (t < 128) {
        float ss = 0.f, qq = 0.f;
        #pragma unroll
        for (int r = 0; r < 8; r++) { ss += sh_s[t + 128 * r]; qq += sh_q[t + 128 * r]; }
        atomicAdd(&sums[t], ss);
        atomicAdd(&sqs[t], qq);
    }
}

// ---------------- Final FC head: 8 nodes per 256-thread block ----------------
// BN affine computed inline from raw sums.
__global__ __launch_bounds__(256) void fc_kernel(
    const float* __restrict__ h2,
    const float* __restrict__ bnS, const float* __restrict__ bnQ,
    const float* __restrict__ bnG, const float* __restrict__ bnBe,
    const int* __restrict__ ptr, const float* __restrict__ gf,
    const float* __restrict__ fcW, const float* __restrict__ fcb,
    const float* __restrict__ fc2W, const float* __restrict__ fc2b,
    float* __restrict__ out)
{
    __shared__ float hc[8][144];
    __shared__ float red[8][128];
    int t = threadIdx.x;
    int nb = blockIdx.x * 8;

    {
        int node_l = t >> 5, li = t & 31;
        int n = nb + node_l;
        float4 v = *reinterpret_cast<const float4*>(&h2[(size_t)n * 128 + li * 4]);
        float4 av, bv;
        bn_ab4(bnS, bnQ, bnG, bnBe, li * 4, av, bv);
        hc[node_l][li * 4 + 0] = fmaxf(v.x * av.x + bv.x, 0.f);
        hc[node_l][li * 4 + 1] = fmaxf(v.y * av.y + bv.y, 0.f);
        hc[node_l][li * 4 + 2] = fmaxf(v.z * av.z + bv.z, 0.f);
        hc[node_l][li * 4 + 3] = fmaxf(v.w * av.w + bv.w, 0.f);
        if (li < 16) {
            int lo = 0, hi = NGRAPH;
            while (lo < hi) {
                int mid = (lo + hi + 1) >> 1;
                if (ptr[mid] <= n) lo = mid; else hi = mid - 1;
            }
            hc[node_l][128 + li] = gf[lo * 16 + li];
        }
    }
    __syncthreads();

    {
        int half = t >> 7, o = t & 127;
        float fb = fcb[o];
        float acc0 = fb, acc1 = fb, acc2 = fb, acc3 = fb;
        const float* h0 = hc[half * 4 + 0];
        const float* h1 = hc[half * 4 + 1];
        const float* h2c = hc[half * 4 + 2];
        const float* h3 = hc[half * 4 + 3];
        #pragma unroll 16
        for (int i = 0; i < 144; i++) {
            float w = fcW[i * 128 + o];
            acc0 += h0[i] * w;
            acc1 += h1[i] * w;
            acc2 += h2c[i] * w;
            acc3 += h3[i] * w;
        }
        float w2 = fc2W[o];
        red[half * 4 + 0][o] = fmaxf(acc0, 0.f) * w2;
        red[half * 4 + 1][o] = fmaxf(acc1, 0.f) * w2;
        red[half * 4 + 2][o] = fmaxf(acc2, 0.f) * w2;
        red[half * 4 + 3][o] = fmaxf(acc3, 0.f) * w2;
    }
    __syncthreads();

    {
        int node_l = t >> 5, li = t & 31;
        float s = red[node_l][li] + red[node_l][li + 32]
                + red[node_l][li + 64] + red[node_l][li + 96];
        s += __shfl_xor(s, 1, 64);
        s += __shfl_xor(s, 2, 64);
        s += __shfl_xor(s, 4, 64);
        s += __shfl_xor(s, 8, 64);
        s += __shfl_xor(s, 16, 64);
        if (li == 0) out[nb + node_l] = s + fc2b[0];
    }
}

// ---------------- launch ----------------
extern "C" void kernel_launch(void* const* d_in, const int* in_sizes, int n_in,
                              void* d_out, int out_size, void* d_ws, size_t ws_size,
                              hipStream_t stream)
{
    const float* x   = (const float*)d_in[0];
    const int*   ei  = (const int*)d_in[1];
    const int*   ptr = (const int*)d_in[2];
    const float* gf  = (const float*)d_in[3];
    const float* Wq0 = (const float*)d_in[4];
    const float* Wk0 = (const float*)d_in[5];
    const float* Wv0 = (const float*)d_in[6];
    const float* Ws0 = (const float*)d_in[7];
    const float* bq0 = (const float*)d_in[8];
    const float* bk0 = (const float*)d_in[9];
    const float* bv0 = (const float*)d_in[10];
    const float* bs0 = (const float*)d_in[11];
    const float* g0  = (const float*)d_in[12];
    const float* be0 = (const float*)d_in[13];
    const float* Wq1 = (const float*)d_in[14];
    const float* Wk1 = (const float*)d_in[15];
    const float* Wv1 = (const float*)d_in[16];
    const float* Ws1 = (const float*)d_in[17];
    const float* bq1 = (const float*)d_in[18];
    const float* bk1 = (const float*)d_in[19];
    const float* bv1 = (const float*)d_in[20];
    const float* bs1 = (const float*)d_in[21];
    const float* g1  = (const float*)d_in[22];
    const float* be1 = (const float*)d_in[23];
    const float* fcW = (const float*)d_in[24];
    const float* fcb = (const float*)d_in[25];
    const float* fc2W= (const float*)d_in[26];
    const float* fc2b= (const float*)d_in[27];
    float* out = (float*)d_out;

    const int* src_p = ei;
    const int* dst_p = ei + N_EDGES;

    char* w = (char*)d_ws;
    const size_t NM = (size_t)N_NODES * 128 * sizeof(float);
    unsigned short* qbf = (unsigned short*)w;  w += (size_t)N_NODES * 128 * sizeof(unsigned short);
    unsigned short* kvb = (unsigned short*)w;  w += (size_t)N_NODES * 256 * sizeof(unsigned short);
    float* h1 = (float*)w;                     w += NM;
    float* h2 = (float*)w;                     w += NM;
    float* stats = (float*)w;                  w += 512 * sizeof(float);
    float* sums0 = stats;
    float* sqs0  = stats + 128;
    float* sums1 = stats + 256;
    float* sqs1  = stats + 384;
    unsigned short* WT0 = (unsigned short*)w;  w += (size_t)512 * 128 * sizeof(unsigned short);
    unsigned short* WT1 = (unsigned short*)w;  w += (size_t)512 * 128 * sizeof(unsigned short);
    int* cnt     = (int*)w;                    w += (size_t)N_NODES * sizeof(int);
    int* row_ptr = (int*)w;                    w += (size_t)(N_NODES + 1) * sizeof(int);
    int* cur     = (int*)w;                    w += (size_t)N_NODES * sizeof(int);
    int* edge_src= (int*)w;                    w += (size_t)N_EDGES * sizeof(int);
    int* bsum    = (int*)w;                    w += 64 * sizeof(int);

    hipMemsetAsync(cnt, 0, (size_t)N_NODES * sizeof(int), stream);
    hipMemsetAsync(stats, 0, 512 * sizeof(float), stream);

    // Weight prep (both layers)
    wprep_kernel<<<4, 256, 0, stream>>>(Wq0, Wk0, Wv0, Ws0, WT0);
    wprep_kernel<<<4, 256, 0, stream>>>(Wq1, Wk1, Wv1, Ws1, WT1);

    // CSR build (reused by both layers)
    hist_kernel<<<3136, 256, 0, stream>>>(dst_p, cnt);
    scan1_kernel<<<49, 256, 0, stream>>>(cnt, row_ptr, bsum);
    scan3_kernel<<<49, 256, 0, stream>>>(row_ptr, cur, bsum);
    scatter_kernel<<<3136, 256, 0, stream>>>(src_p, dst_p, cur, edge_src);

    // Layer 0
    gemm_mfma<<<784, 512, 0, stream>>>(x, WT0,
        bq0, bk0, bv0, bs0, qbf, kvb, h1, nullptr, nullptr, nullptr, nullptr);
    agg_kernel<<<12544, 256, 0, stream>>>(qbf, kvb, row_ptr, edge_src, h1);
    bn_stats<<<784, 256, 0, stream>>>(h1, sums0, sqs0);

    // Layer 1 (BN+ReLU from raw sums fused into GEMM A-staging)
    gemm_mfma<<<784, 512, 0, stream>>>(h1, WT1,
        bq1, bk1, bv1, bs1, qbf, kvb, h2, sums0, sqs0, g0, be0);
    agg_kernel<<<12544, 256, 0, stream>>>(qbf, kvb, row_ptr, edge_src, h2);
    bn_stats<<<784, 256, 0, stream>>>(h2, sums1, sqs1);

    // Head: BN(from sums) + ReLU + concat(global) + FC + ReLU + FC2
    fc_kernel<<<6272, 256, 0, stream>>>(h2, sums1, sqs1, g1, be1, ptr, gf,
        fcW, fcb, fc2W, fc2b, out);
}